// Round 1
// baseline (2313.431 us; speedup 1.0000x reference)
//
#include <hip/hip_runtime.h>
#include <hip/hip_bf16.h>

#define B 512
#define N 102
#define P 12
#define H 256
#define M 4
#define E 3
#define HOPS 2
#define NEG (-1e9f)

typedef __hip_bfloat16 bf16;

__device__ __forceinline__ float b2f(bf16 v) { return __bfloat162float(v); }
__device__ __forceinline__ bf16 f2b(float v) { return __float2bfloat16(v); }

// ---------------- K1: embedding h = nf @ W_emb ----------------
__global__ __launch_bounds__(256) void embed_k(const float* __restrict__ nf,
                                               const float* __restrict__ W_emb,
                                               bf16* __restrict__ h) {
    int row = blockIdx.x;           // b*N + n
    int k = threadIdx.x;            // 0..255
    __shared__ float f[P];
    if (k < P) f[k] = nf[(size_t)row * P + k];
    __syncthreads();
    float s = 0.f;
#pragma unroll
    for (int p = 0; p < P; ++p) s += f[p] * W_emb[p * H + k];
    h[(size_t)row * H + k] = f2b(s);
}

// ---------------- K2: msg[b,n,e*H+k] = sum_m A[b,e,n,m]*h[b,m,k] ----------------
__global__ __launch_bounds__(256) void msg_k(const float* __restrict__ A,
                                             const bf16* __restrict__ h,
                                             bf16* __restrict__ msg) {
    int bid = blockIdx.x;
    int nt = bid % 3;
    int e = (bid / 3) % E;
    int b = bid / (3 * E);
    int n0 = nt * 34;
    int tid = threadIdx.x;

    __shared__ float As[34][34];
    __shared__ float hs[34][H];

    float acc[34];
#pragma unroll
    for (int i = 0; i < 34; ++i) acc[i] = 0.f;

    for (int m0 = 0; m0 < N; m0 += 34) {
        for (int idx = tid; idx < 34 * 34; idx += 256) {
            int i = idx / 34, mm = idx % 34;
            As[i][mm] = A[(((size_t)b * E + e) * N + (n0 + i)) * N + (m0 + mm)];
        }
        for (int idx = tid; idx < 34 * H; idx += 256) {
            int mm = idx >> 8, k = idx & 255;
            hs[mm][k] = b2f(h[((size_t)b * N + (m0 + mm)) * H + k]);
        }
        __syncthreads();
        for (int mm = 0; mm < 34; ++mm) {
            float hv = hs[mm][tid];
#pragma unroll
            for (int i = 0; i < 34; ++i) acc[i] += As[i][mm] * hv;
        }
        __syncthreads();
    }
#pragma unroll
    for (int i = 0; i < 34; ++i)
        msg[((size_t)b * N + (n0 + i)) * (E * H) + e * H + tid] = f2b(acc[i]);
}

// ------------- K3: h_out = relu(msg @ W_rel[hop] + h_in @ W_self[hop]) -------------
// rows R = B*N = 52224, K = 768 (msg) + 256 (h), cols = 256. Tile 64x64, thread 4x4.
__global__ __launch_bounds__(256) void hop_combine(const bf16* __restrict__ msg,
                                                   const bf16* __restrict__ hin,
                                                   const float* __restrict__ Wrel,   // [768,256]
                                                   const float* __restrict__ Wself,  // [256,256]
                                                   bf16* __restrict__ hout) {
    __shared__ float xs[16][64];  // [kk][row]
    __shared__ float ws[16][64];  // [kk][col]
    int bid = blockIdx.x;
    int rt = bid >> 2, ct = bid & 3;
    int row0 = rt * 64, col0 = ct * 64;
    int tid = threadIdx.x;
    int tx = tid & 15, ty = tid >> 4;

    float acc[4][4];
#pragma unroll
    for (int i = 0; i < 4; ++i)
#pragma unroll
        for (int j = 0; j < 4; ++j) acc[i][j] = 0.f;

    for (int j0 = 0; j0 < 1024; j0 += 16) {
        for (int idx = tid; idx < 64 * 16; idx += 256) {
            int r = idx >> 4, c = idx & 15;
            int j = j0 + c;
            float v;
            if (j < 768) v = b2f(msg[(size_t)(row0 + r) * 768 + j]);
            else         v = b2f(hin[(size_t)(row0 + r) * H + (j - 768)]);
            xs[c][r] = v;
        }
        const float* Wp = (j0 < 768) ? Wrel : Wself;
        int jj0 = (j0 < 768) ? j0 : (j0 - 768);
        for (int idx = tid; idx < 16 * 64; idx += 256) {
            int r = idx >> 6, c = idx & 63;
            ws[r][c] = Wp[(size_t)(jj0 + r) * H + col0 + c];
        }
        __syncthreads();
#pragma unroll
        for (int kk = 0; kk < 16; ++kk) {
            float xv[4], wv[4];
#pragma unroll
            for (int i = 0; i < 4; ++i) xv[i] = xs[kk][ty * 4 + i];
#pragma unroll
            for (int j = 0; j < 4; ++j) wv[j] = ws[kk][tx * 4 + j];
#pragma unroll
            for (int i = 0; i < 4; ++i)
#pragma unroll
                for (int j = 0; j < 4; ++j) acc[i][j] += xv[i] * wv[j];
        }
        __syncthreads();
    }
#pragma unroll
    for (int i = 0; i < 4; ++i) {
        int row = row0 + ty * 4 + i;
#pragma unroll
        for (int j = 0; j < 4; ++j) {
            int col = col0 + tx * 4 + j;
            float v = acc[i][j];
            v = v > 0.f ? v : 0.f;
            hout[(size_t)row * H + col] = f2b(v);
        }
    }
}

// ---------------- K4: enc_mean ----------------
__global__ __launch_bounds__(256) void mean_k(const bf16* __restrict__ enc,
                                              float* __restrict__ enc_mean) {
    int b = blockIdx.x, k = threadIdx.x;
    float s = 0.f;
    for (int n = 0; n < N; ++n) s += b2f(enc[((size_t)b * N + n) * H + k]);
    enc_mean[(size_t)b * H + k] = s * (1.f / (float)N);
}

// ---------------- K5: qconst[m,h], vsum[m,h] ----------------
__global__ __launch_bounds__(256) void prep_k(const float* __restrict__ W_q,
                                              const float* __restrict__ Vec,
                                              const float* __restrict__ dec,
                                              const float* __restrict__ v1,
                                              float* __restrict__ qconst,
                                              float* __restrict__ vsum) {
    int m = blockIdx.x, hh = threadIdx.x;
    __shared__ float dls[H], vls[H];
    dls[hh] = dec[hh];
    vls[hh] = v1[hh];
    __syncthreads();
    const float* Wm = W_q + (size_t)m * (3 * H) * H;
    float s = 0.f;
    for (int f = 0; f < H; ++f)
        s += dls[f] * Wm[(H + f) * H + hh] + vls[f] * Wm[(2 * H + f) * H + hh];
    qconst[m * H + hh] = s;
    float vs = 0.f;
    const float* Vr = Vec + ((size_t)m * H + hh) * H;
    for (int k = 0; k < H; ++k) vs += Vr[k];
    vsum[m * H + hh] = vs;
}

// ---------------- K6: q[b,m,h] = enc_mean[b] @ W_q[m,0:H] + qconst ----------------
__global__ __launch_bounds__(256) void q_k(const float* __restrict__ enc_mean,
                                           const float* __restrict__ W_q,
                                           const float* __restrict__ qconst,
                                           float* __restrict__ qbuf) {
    int bid = blockIdx.x;
    int b = bid >> 2, m = bid & 3;
    int hh = threadIdx.x;
    __shared__ float em[H];
    em[hh] = enc_mean[(size_t)b * H + hh];
    __syncthreads();
    const float* Wm = W_q + (size_t)m * (3 * H) * H;
    float s = qconst[m * H + hh];
    for (int f = 0; f < H; ++f) s += em[f] * Wm[f * H + hh];
    qbuf[((size_t)b * M + m) * H + hh] = s;
}

// ------- K7: glimpse scores[b,m,n] = sum_h tanh(q[b,m,h] + (enc[b,n]@W_ref[m])[h]) * vsum[m,h] -------
__global__ __launch_bounds__(256) void glimpse_k(const bf16* __restrict__ enc,
                                                 const float* __restrict__ W_ref,
                                                 const float* __restrict__ qbuf,
                                                 const float* __restrict__ vsum,
                                                 float* __restrict__ scores) {
    int bid = blockIdx.x;
    int b = bid / 12;
    int rem = bid % 12;
    int m = rem / 3, nt = rem % 3;
    int n0 = nt * 34;
    int tid = threadIdx.x;

    __shared__ float es[16][34];
    __shared__ float ws2[16][H];
    __shared__ float part[4][34];

    float acc[34];
#pragma unroll
    for (int i = 0; i < 34; ++i) acc[i] = 0.f;

    const float* Wm = W_ref + (size_t)m * H * H;
    for (int k0 = 0; k0 < H; k0 += 16) {
        for (int idx = tid; idx < 34 * 16; idx += 256) {
            int r = idx / 16, c = idx % 16;
            es[c][r] = b2f(enc[((size_t)b * N + (n0 + r)) * H + k0 + c]);
        }
        for (int idx = tid; idx < 16 * H; idx += 256) {
            int r = idx >> 8, c = idx & 255;
            ws2[r][c] = Wm[(size_t)(k0 + r) * H + c];
        }
        __syncthreads();
        for (int kk = 0; kk < 16; ++kk) {
            float wv = ws2[kk][tid];
#pragma unroll
            for (int i = 0; i < 34; ++i) acc[i] += es[kk][i] * wv;
        }
        __syncthreads();
    }

    float qv = qbuf[((size_t)b * M + m) * H + tid];
    float vs = vsum[m * H + tid];
    int lane = tid & 63, wid = tid >> 6;
#pragma unroll
    for (int i = 0; i < 34; ++i) {
        float v = tanhf(qv + acc[i]) * vs;
        v += __shfl_down(v, 32, 64);
        v += __shfl_down(v, 16, 64);
        v += __shfl_down(v, 8, 64);
        v += __shfl_down(v, 4, 64);
        v += __shfl_down(v, 2, 64);
        v += __shfl_down(v, 1, 64);
        if (lane == 0) part[wid][i] = v;
    }
    __syncthreads();
    if (tid < 34) {
        float s = part[0][tid] + part[1][tid] + part[2][tid] + part[3][tid];
        scores[((size_t)b * M + m) * N + n0 + tid] = s;
    }
}

// ---------------- K8: masked softmax over n + ctx = a @ enc ----------------
__global__ __launch_bounds__(256) void softmax_ctx_k(const float* __restrict__ scores,
                                                     const int* __restrict__ mask,
                                                     const bf16* __restrict__ enc,
                                                     float* __restrict__ ctx) {
    int bid = blockIdx.x;
    int b = bid >> 2, m = bid & 3;
    int tid = threadIdx.x;
    __shared__ float a[N];
    __shared__ float mx_s, sum_s;
    if (tid < N) {
        float s = (mask[(size_t)b * N + tid] > 0) ? NEG : scores[((size_t)b * M + m) * N + tid];
        a[tid] = s;
    }
    __syncthreads();
    if (tid == 0) {
        float mx = -3e38f;
        for (int n = 0; n < N; ++n) mx = fmaxf(mx, a[n]);
        mx_s = mx;
    }
    __syncthreads();
    if (tid < N) a[tid] = expf(a[tid] - mx_s);
    __syncthreads();
    if (tid == 0) {
        float s = 0.f;
        for (int n = 0; n < N; ++n) s += a[n];
        sum_s = 1.f / s;
    }
    __syncthreads();
    float c = 0.f;
    for (int n = 0; n < N; ++n)
        c += a[n] * b2f(enc[((size_t)b * N + n) * H + tid]);
    ctx[((size_t)b * M + m) * H + tid] = c * sum_s;
}

// ---------------- K9: query2 = ctx @ W_mh ; q2 = query2 @ W_q2 ----------------
__global__ __launch_bounds__(256) void query2_k(const float* __restrict__ ctx,
                                                const float* __restrict__ W_mh,
                                                const float* __restrict__ W_q2,
                                                float* __restrict__ q2) {
    int b = blockIdx.x;
    int tid = threadIdx.x;
    __shared__ float cx[M * H];
    __shared__ float qy[H];
    for (int idx = tid; idx < M * H; idx += 256) cx[idx] = ctx[(size_t)b * M * H + idx];
    __syncthreads();
    float acc = 0.f;
    for (int j = 0; j < M * H; ++j) acc += cx[j] * W_mh[(size_t)j * H + tid];
    qy[tid] = acc;
    __syncthreads();
    float acc2 = 0.f;
    for (int k = 0; k < H; ++k) acc2 += qy[k] * W_q2[(size_t)k * H + tid];
    q2[(size_t)b * H + tid] = acc2;
}

// ------- K10: u2[b,n] = sum_h Vec2[h] * tanh(q2[b,h] + (enc[b,n]@W_ref2)[h]) -------
__global__ __launch_bounds__(256) void final_scores_k(const bf16* __restrict__ enc,
                                                      const float* __restrict__ W_ref2,
                                                      const float* __restrict__ q2,
                                                      const float* __restrict__ Vec2,
                                                      float* __restrict__ u2) {
    int bid = blockIdx.x;
    int b = bid / 3, nt = bid % 3;
    int n0 = nt * 34;
    int tid = threadIdx.x;

    __shared__ float es[16][34];
    __shared__ float ws2[16][H];
    __shared__ float part[4][34];

    float acc[34];
#pragma unroll
    for (int i = 0; i < 34; ++i) acc[i] = 0.f;

    for (int k0 = 0; k0 < H; k0 += 16) {
        for (int idx = tid; idx < 34 * 16; idx += 256) {
            int r = idx / 16, c = idx % 16;
            es[c][r] = b2f(enc[((size_t)b * N + (n0 + r)) * H + k0 + c]);
        }
        for (int idx = tid; idx < 16 * H; idx += 256) {
            int r = idx >> 8, c = idx & 255;
            ws2[r][c] = W_ref2[(size_t)(k0 + r) * H + c];
        }
        __syncthreads();
        for (int kk = 0; kk < 16; ++kk) {
            float wv = ws2[kk][tid];
#pragma unroll
            for (int i = 0; i < 34; ++i) acc[i] += es[kk][i] * wv;
        }
        __syncthreads();
    }

    float qv = q2[(size_t)b * H + tid];
    float vs = Vec2[tid];
    int lane = tid & 63, wid = tid >> 6;
#pragma unroll
    for (int i = 0; i < 34; ++i) {
        float v = tanhf(qv + acc[i]) * vs;
        v += __shfl_down(v, 32, 64);
        v += __shfl_down(v, 16, 64);
        v += __shfl_down(v, 8, 64);
        v += __shfl_down(v, 4, 64);
        v += __shfl_down(v, 2, 64);
        v += __shfl_down(v, 1, 64);
        if (lane == 0) part[wid][i] = v;
    }
    __syncthreads();
    if (tid < 34) {
        float s = part[0][tid] + part[1][tid] + part[2][tid] + part[3][tid];
        u2[(size_t)b * N + n0 + tid] = s;
    }
}

// ---------------- K11: clip + mask + log_softmax ----------------
__global__ __launch_bounds__(128) void final_out_k(const float* __restrict__ u2,
                                                   const int* __restrict__ mask,
                                                   float* __restrict__ out) {
    int b = blockIdx.x;
    int tid = threadIdx.x;
    __shared__ float sv[N];
    __shared__ float mx_s, lse_s;
    if (tid < N) {
        float u = 10.f * tanhf(u2[(size_t)b * N + tid]);
        if (mask[(size_t)b * N + tid] > 0) u = NEG;
        sv[tid] = u;
    }
    __syncthreads();
    if (tid == 0) {
        float mx = -3e38f;
        for (int n = 0; n < N; ++n) mx = fmaxf(mx, sv[n]);
        float s = 0.f;
        for (int n = 0; n < N; ++n) s += expf(sv[n] - mx);
        mx_s = mx;
        lse_s = logf(s);
    }
    __syncthreads();
    if (tid < N) out[(size_t)b * N + tid] = (sv[tid] - mx_s) - lse_s;
}

extern "C" void kernel_launch(void* const* d_in, const int* in_sizes, int n_in,
                              void* d_out, int out_size, void* d_ws, size_t ws_size,
                              hipStream_t stream) {
    const float* nf     = (const float*)d_in[0];
    const float* adj    = (const float*)d_in[1];
    const int*   mask   = (const int*)d_in[2];
    const float* W_emb  = (const float*)d_in[3];
    const float* W_rel  = (const float*)d_in[4];
    const float* W_self = (const float*)d_in[5];
    const float* Vec    = (const float*)d_in[6];
    const float* W_q    = (const float*)d_in[7];
    const float* W_ref  = (const float*)d_in[8];
    const float* W_mh   = (const float*)d_in[9];
    const float* Vec2   = (const float*)d_in[10];
    const float* W_q2   = (const float*)d_in[11];
    const float* W_ref2 = (const float*)d_in[12];
    const float* dec    = (const float*)d_in[13];
    const float* v_1    = (const float*)d_in[14];
    float* out = (float*)d_out;

    char* ws = (char*)d_ws;
    size_t off = 0;
    auto alloc = [&](size_t bytes) -> char* {
        char* p = ws + off;
        off += (bytes + 255) & ~(size_t)255;
        return p;
    };
    bf16* h0    = (bf16*)alloc((size_t)B * N * H * sizeof(bf16));
    bf16* h1    = (bf16*)alloc((size_t)B * N * H * sizeof(bf16));
    bf16* msgb  = (bf16*)alloc((size_t)B * N * E * H * sizeof(bf16));
    float* enc_mean = (float*)alloc((size_t)B * H * sizeof(float));
    float* qconst   = (float*)alloc((size_t)M * H * sizeof(float));
    float* vsumb    = (float*)alloc((size_t)M * H * sizeof(float));
    float* qbuf     = (float*)alloc((size_t)B * M * H * sizeof(float));
    float* scoresb  = (float*)alloc((size_t)B * M * N * sizeof(float));
    float* ctxb     = (float*)alloc((size_t)B * M * H * sizeof(float));
    float* q2b      = (float*)alloc((size_t)B * H * sizeof(float));
    float* u2b      = (float*)alloc((size_t)B * N * sizeof(float));

    embed_k<<<B * N, 256, 0, stream>>>(nf, W_emb, h0);

    bf16* cur = h0;
    bf16* nxt = h1;
    for (int hop = 0; hop < HOPS; ++hop) {
        msg_k<<<B * E * 3, 256, 0, stream>>>(adj, cur, msgb);
        hop_combine<<<(B * N / 64) * 4, 256, 0, stream>>>(
            msgb, cur,
            W_rel + (size_t)hop * E * H * H,
            W_self + (size_t)hop * H * H,
            nxt);
        bf16* t = cur; cur = nxt; nxt = t;
    }
    const bf16* enc = cur;

    mean_k<<<B, 256, 0, stream>>>(enc, enc_mean);
    prep_k<<<M, 256, 0, stream>>>(W_q, Vec, dec, v_1, qconst, vsumb);
    q_k<<<B * M, 256, 0, stream>>>(enc_mean, W_q, qconst, qbuf);
    glimpse_k<<<B * M * 3, 256, 0, stream>>>(enc, W_ref, qbuf, vsumb, scoresb);
    softmax_ctx_k<<<B * M, 256, 0, stream>>>(scoresb, mask, enc, ctxb);
    query2_k<<<B, 256, 0, stream>>>(ctxb, W_mh, W_q2, q2b);
    final_scores_k<<<B * 3, 256, 0, stream>>>(enc, W_ref2, q2b, Vec2, u2b);
    final_out_k<<<B, 128, 0, stream>>>(u2b, mask, out);
}

// Round 2
// 638.915 us; speedup vs baseline: 3.6209x; 3.6209x over previous
//
#include <hip/hip_runtime.h>
#include <hip/hip_bf16.h>

#define B 512
#define N 102
#define Pdim 12
#define H 256
#define M 4
#define E 3
#define NEG (-1e9f)
#define RT 52224   // B*N

typedef __hip_bfloat16 bf16;
typedef __attribute__((ext_vector_type(8))) short short8;
typedef __attribute__((ext_vector_type(4))) float f32x4;

__device__ __forceinline__ float b2f(bf16 v) { return __bfloat162float(v); }
__device__ __forceinline__ bf16 f2b(float v) { return __float2bfloat16(v); }
__device__ __forceinline__ short f2bs(float v) {
    bf16 t = __float2bfloat16(v);
    return *reinterpret_cast<short*>(&t);
}
__device__ __forceinline__ float fast_tanh(float x) {
    float e = __expf(2.f * x);
    return 1.f - 2.f / (e + 1.f);
}

// ---------------- weight prep: build bf16 transposed weights ----------------
// wtcat[hop][c][k] (c:256 out, k:1024 = 3*256 rel + 256 self), wrefT[(m*256+c)][k], wref2T[c][k]
__global__ __launch_bounds__(256) void wt_prep(const float* __restrict__ Wrel,
                                               const float* __restrict__ Wself,
                                               const float* __restrict__ Wref,
                                               const float* __restrict__ Wref2,
                                               short* __restrict__ wtcat,
                                               short* __restrict__ wrefT,
                                               short* __restrict__ wref2T) {
    int idx = blockIdx.x * 256 + threadIdx.x;
    if (idx < 524288) {
        int hop = idx >> 18;
        int r = idx & 262143;
        int c = r >> 10, k = r & 1023;
        float v;
        if (k < 768) {
            int e = k >> 8, h = k & 255;
            v = Wrel[(((size_t)hop * E + e) * H + h) * H + c];
        } else {
            int h = k - 768;
            v = Wself[((size_t)hop * H + h) * H + c];
        }
        wtcat[idx] = f2bs(v);
    } else if (idx < 786432) {
        int r = idx - 524288;            // (m*256+c)*256 + k
        int row = r >> 8, k = r & 255;
        int m = row >> 8, c = row & 255;
        wrefT[r] = f2bs(Wref[((size_t)m * H + k) * H + c]);
    } else if (idx < 851968) {
        int r = idx - 786432;
        int c = r >> 8, k = r & 255;
        wref2T[r] = f2bs(Wref2[k * H + c]);
    }
}

// ---------------- K1: embedding h = nf @ W_emb ----------------
__global__ __launch_bounds__(256) void embed_k(const float* __restrict__ nf,
                                               const float* __restrict__ W_emb,
                                               bf16* __restrict__ h) {
    int row = blockIdx.x;
    int k = threadIdx.x;
    __shared__ float f[Pdim];
    if (k < Pdim) f[k] = nf[(size_t)row * Pdim + k];
    __syncthreads();
    float s = 0.f;
#pragma unroll
    for (int p = 0; p < Pdim; ++p) s += f[p] * W_emb[p * H + k];
    h[(size_t)row * H + k] = f2b(s);
}

// ---------------- transpose: hT[b][c][m] = h[b*N+m][c], zero-padded m>=102 ----------------
__global__ __launch_bounds__(256) void transpose_h(const bf16* __restrict__ h,
                                                   bf16* __restrict__ hT) {
    int b = blockIdx.x >> 2, cc = blockIdx.x & 3;
    int tid = threadIdx.x;
    __shared__ short ts[102 * 68];
    const short* hs = (const short*)h;
    for (int idx = tid; idx < 102 * 64; idx += 256) {
        int m = idx >> 6, c = idx & 63;
        ts[m * 68 + c] = hs[((size_t)b * N + m) * H + cc * 64 + c];
    }
    __syncthreads();
    short* ht = (short*)hT;
    for (int idx = tid; idx < 64 * 128; idx += 256) {
        int c = idx >> 7, m = idx & 127;
        short v = (m < N) ? ts[m * 68 + c] : (short)0;
        ht[((size_t)b * H + cc * 64 + c) * 128 + m] = v;
    }
}

// ---------------- msg MFMA: msg[b,n,e*256+c] = sum_m A[b,e,n,m] * h[b,m,c] ----------------
__global__ __launch_bounds__(256) void msg_mfma(const float* __restrict__ A,
                                                const bf16* __restrict__ hT,
                                                bf16* __restrict__ msgb) {
    int b = blockIdx.x, e = blockIdx.y;
    int tid = threadIdx.x;
    int w = tid >> 6, l = tid & 63;
    int cg = l & 15, rg = l >> 4;
    __shared__ short As[112 * 136];
    const float* Ab = A + (((size_t)b * E + e) * N) * N;
    for (int idx = tid; idx < 112 * 128; idx += 256) {
        int n = idx >> 7, m = idx & 127;
        float v = (n < N && m < N) ? Ab[n * N + m] : 0.f;
        As[n * 136 + m] = f2bs(v);
    }
    __syncthreads();

    f32x4 acc[7][4];
#pragma unroll
    for (int i = 0; i < 7; ++i)
#pragma unroll
        for (int j = 0; j < 4; ++j) acc[i][j] = (f32x4){0.f, 0.f, 0.f, 0.f};

    const short8* hT8 = (const short8*)hT;
#pragma unroll
    for (int step = 0; step < 4; ++step) {
        int m0 = step * 32;
        short8 bfr[4];
#pragma unroll
        for (int nt = 0; nt < 4; ++nt) {
            int col = w * 64 + nt * 16 + cg;
            bfr[nt] = hT8[((size_t)b * H + col) * 16 + (m0 >> 3) + rg];
        }
#pragma unroll
        for (int mt = 0; mt < 7; ++mt) {
            int n = mt * 16 + cg;
            short8 af = *(const short8*)(&As[n * 136 + m0 + rg * 8]);
#pragma unroll
            for (int nt = 0; nt < 4; ++nt)
                acc[mt][nt] = __builtin_amdgcn_mfma_f32_16x16x32_bf16(af, bfr[nt], acc[mt][nt], 0, 0, 0);
        }
    }
#pragma unroll
    for (int mt = 0; mt < 7; ++mt)
#pragma unroll
        for (int reg = 0; reg < 4; ++reg) {
            int n = mt * 16 + rg * 4 + reg;
            if (n < N) {
#pragma unroll
                for (int nt = 0; nt < 4; ++nt) {
                    int col = w * 64 + nt * 16 + cg;
                    msgb[((size_t)b * N + n) * 768 + e * H + col] = f2b(acc[mt][nt][reg]);
                }
            }
        }
}

// ------------- hop MFMA: hout = relu([msg|hin] @ Wcat),  X:[RT,1024], W^T:[256,1024] -------------
__global__ __launch_bounds__(256) void hop_mfma(const bf16* __restrict__ msgb,
                                                const bf16* __restrict__ hin,
                                                const short* __restrict__ wt,
                                                bf16* __restrict__ hout) {
    int rt = blockIdx.x, ct = blockIdx.y;
    int r0 = rt * 128, c0 = ct * 128;
    int tid = threadIdx.x;
    int w = tid >> 6, l = tid & 63;
    int wr = w >> 1, wc = w & 1;
    int cg = l & 15, rg = l >> 4;
    __shared__ short As[128 * 72];

    f32x4 acc[4][4];
#pragma unroll
    for (int i = 0; i < 4; ++i)
#pragma unroll
        for (int j = 0; j < 4; ++j) acc[i][j] = (f32x4){0.f, 0.f, 0.f, 0.f};

    const short8* wt8 = (const short8*)wt;
    const short* msgs = (const short*)msgb;
    const short* hins = (const short*)hin;

    for (int k0 = 0; k0 < 1024; k0 += 64) {
        __syncthreads();
#pragma unroll
        for (int i = 0; i < 4; ++i) {
            int cid = tid + i * 256;
            int n = cid >> 3, k8 = cid & 7;
            int row = r0 + n, kk = k0 + k8 * 8;
            const short* src = (kk < 768) ? (msgs + (size_t)row * 768 + kk)
                                          : (hins + (size_t)row * 256 + (kk - 768));
            *(short8*)(&As[n * 72 + k8 * 8]) = *(const short8*)src;
        }
        __syncthreads();
#pragma unroll
        for (int half = 0; half < 2; ++half) {
            int kk = half * 32;
            short8 bfr[4];
#pragma unroll
            for (int nt = 0; nt < 4; ++nt) {
                int c = c0 + wc * 64 + nt * 16 + cg;
                bfr[nt] = wt8[(size_t)c * 128 + ((k0 + kk) >> 3) + rg];
            }
#pragma unroll
            for (int mt = 0; mt < 4; ++mt) {
                int n = wr * 64 + mt * 16 + cg;
                short8 af = *(const short8*)(&As[n * 72 + kk + rg * 8]);
#pragma unroll
                for (int nt = 0; nt < 4; ++nt)
                    acc[mt][nt] = __builtin_amdgcn_mfma_f32_16x16x32_bf16(af, bfr[nt], acc[mt][nt], 0, 0, 0);
            }
        }
    }
#pragma unroll
    for (int mt = 0; mt < 4; ++mt)
#pragma unroll
        for (int reg = 0; reg < 4; ++reg) {
            int row = r0 + wr * 64 + mt * 16 + rg * 4 + reg;
#pragma unroll
            for (int nt = 0; nt < 4; ++nt) {
                int c = c0 + wc * 64 + nt * 16 + cg;
                float v = acc[mt][nt][reg];
                hout[(size_t)row * H + c] = f2b(v > 0.f ? v : 0.f);
            }
        }
}

// ------- head MFMA: out[b,n] = sum_c fast_tanh(q[b,c] + (enc@W^T)[r,c]) * vs[c], fused -------
// grid.y = head m. WT has rows (m*256+c), q index (qb + m*256)[b*qbs + c], out (outp+m*102)[b*obs+n]
__global__ __launch_bounds__(256) void head_mfma(const bf16* __restrict__ X,
                                                 const short* __restrict__ WT,
                                                 const float* __restrict__ qb, int qbs,
                                                 const float* __restrict__ vsb,
                                                 float* __restrict__ outp, int obs) {
    int rt = blockIdx.x, m = blockIdx.y;
    int r0 = rt * 64;
    int tid = threadIdx.x;
    int w = tid >> 6, l = tid & 63;
    int wr = w >> 1, wc = w & 1;
    int cg = l & 15, rg = l >> 4;
    __shared__ short As[64 * 264];
    __shared__ float part[2][64];

    const short8* wt8 = (const short8*)(WT + (size_t)m * H * H);
    const float* qp = qb + m * H;
    const float* vsp = vsb + m * H;
    float* op = outp + m * N;
    const short* Xs = (const short*)X;

#pragma unroll
    for (int i = 0; i < 8; ++i) {
        int cid = tid + i * 256;
        int n = cid >> 5, k8 = cid & 31;
        *(short8*)(&As[n * 264 + k8 * 8]) = *(const short8*)(Xs + (size_t)(r0 + n) * H + k8 * 8);
    }
    __syncthreads();

    f32x4 acc[2][8];
#pragma unroll
    for (int i = 0; i < 2; ++i)
#pragma unroll
        for (int j = 0; j < 8; ++j) acc[i][j] = (f32x4){0.f, 0.f, 0.f, 0.f};

#pragma unroll
    for (int k0 = 0; k0 < 256; k0 += 32) {
        short8 bfr[8];
#pragma unroll
        for (int nt = 0; nt < 8; ++nt) {
            int c = wc * 128 + nt * 16 + cg;
            bfr[nt] = wt8[c * 32 + (k0 >> 3) + rg];
        }
#pragma unroll
        for (int mt = 0; mt < 2; ++mt) {
            int n = wr * 32 + mt * 16 + cg;
            short8 af = *(const short8*)(&As[n * 264 + k0 + rg * 8]);
#pragma unroll
            for (int nt = 0; nt < 8; ++nt)
                acc[mt][nt] = __builtin_amdgcn_mfma_f32_16x16x32_bf16(af, bfr[nt], acc[mt][nt], 0, 0, 0);
        }
    }

    float vsl[8];
#pragma unroll
    for (int nt = 0; nt < 8; ++nt) vsl[nt] = vsp[wc * 128 + nt * 16 + cg];
#pragma unroll
    for (int mt = 0; mt < 2; ++mt)
#pragma unroll
        for (int reg = 0; reg < 4; ++reg) {
            int rl = wr * 32 + mt * 16 + rg * 4 + reg;
            int r = r0 + rl;
            int b = r / N;
            const float* qrow = qp + (size_t)b * qbs;
            float s = 0.f;
#pragma unroll
            for (int nt = 0; nt < 8; ++nt) {
                int c = wc * 128 + nt * 16 + cg;
                s += fast_tanh(qrow[c] + acc[mt][nt][reg]) * vsl[nt];
            }
            s += __shfl_xor(s, 1, 64);
            s += __shfl_xor(s, 2, 64);
            s += __shfl_xor(s, 4, 64);
            s += __shfl_xor(s, 8, 64);
            if (cg == 0) part[wc][rl] = s;
        }
    __syncthreads();
    if (tid < 64) {
        int r = r0 + tid;
        int b = r / N, n = r - b * N;
        op[(size_t)b * obs + n] = part[0][tid] + part[1][tid];
    }
}

// ---------------- enc_mean ----------------
__global__ __launch_bounds__(256) void mean_k(const bf16* __restrict__ enc,
                                              float* __restrict__ enc_mean) {
    int b = blockIdx.x, k = threadIdx.x;
    float s = 0.f;
    for (int n = 0; n < N; ++n) s += b2f(enc[((size_t)b * N + n) * H + k]);
    enc_mean[(size_t)b * H + k] = s * (1.f / (float)N);
}

// ---------------- qconst[m,h], vsum[m,h] ----------------
__global__ __launch_bounds__(256) void prep_k(const float* __restrict__ W_q,
                                              const float* __restrict__ Vec,
                                              const float* __restrict__ dec,
                                              const float* __restrict__ v1,
                                              float* __restrict__ qconst,
                                              float* __restrict__ vsum) {
    int m = blockIdx.x, hh = threadIdx.x;
    __shared__ float dls[H], vls[H];
    dls[hh] = dec[hh];
    vls[hh] = v1[hh];
    __syncthreads();
    const float* Wm = W_q + (size_t)m * (3 * H) * H;
    float s = 0.f;
    for (int f = 0; f < H; ++f)
        s += dls[f] * Wm[(H + f) * H + hh] + vls[f] * Wm[(2 * H + f) * H + hh];
    qconst[m * H + hh] = s;
    float vs = 0.f;
    const float* Vr = Vec + ((size_t)m * H + hh) * H;
    for (int k = 0; k < H; ++k) vs += Vr[k];
    vsum[m * H + hh] = vs;
}

// ---------------- q[b,m,h] ----------------
__global__ __launch_bounds__(256) void q_k(const float* __restrict__ enc_mean,
                                           const float* __restrict__ W_q,
                                           const float* __restrict__ qconst,
                                           float* __restrict__ qbuf) {
    int bid = blockIdx.x;
    int b = bid >> 2, m = bid & 3;
    int hh = threadIdx.x;
    __shared__ float em[H];
    em[hh] = enc_mean[(size_t)b * H + hh];
    __syncthreads();
    const float* Wm = W_q + (size_t)m * (3 * H) * H;
    float s = qconst[m * H + hh];
    for (int f = 0; f < H; ++f) s += em[f] * Wm[f * H + hh];
    qbuf[((size_t)b * M + m) * H + hh] = s;
}

// ---------------- masked softmax + ctx ----------------
__global__ __launch_bounds__(256) void softmax_ctx_k(const float* __restrict__ scores,
                                                     const int* __restrict__ mask,
                                                     const bf16* __restrict__ enc,
                                                     float* __restrict__ ctx) {
    int bid = blockIdx.x;
    int b = bid >> 2, m = bid & 3;
    int tid = threadIdx.x;
    __shared__ float a[N];
    __shared__ float mx_s, sum_s;
    if (tid < N) {
        float s = (mask[(size_t)b * N + tid] > 0) ? NEG : scores[((size_t)b * M + m) * N + tid];
        a[tid] = s;
    }
    __syncthreads();
    if (tid == 0) {
        float mx = -3e38f;
        for (int n = 0; n < N; ++n) mx = fmaxf(mx, a[n]);
        mx_s = mx;
    }
    __syncthreads();
    if (tid < N) a[tid] = __expf(a[tid] - mx_s);
    __syncthreads();
    if (tid == 0) {
        float s = 0.f;
        for (int n = 0; n < N; ++n) s += a[n];
        sum_s = 1.f / s;
    }
    __syncthreads();
    float c = 0.f;
    for (int n = 0; n < N; ++n)
        c += a[n] * b2f(enc[((size_t)b * N + n) * H + tid]);
    ctx[((size_t)b * M + m) * H + tid] = c * sum_s;
}

// ---------------- query2 = (ctx @ W_mh) @ W_q2 ----------------
__global__ __launch_bounds__(256) void query2_k(const float* __restrict__ ctx,
                                                const float* __restrict__ W_mh,
                                                const float* __restrict__ W_q2,
                                                float* __restrict__ q2) {
    int b = blockIdx.x;
    int tid = threadIdx.x;
    __shared__ float cx[M * H];
    __shared__ float qy[H];
    for (int idx = tid; idx < M * H; idx += 256) cx[idx] = ctx[(size_t)b * M * H + idx];
    __syncthreads();
    float acc = 0.f;
    for (int j = 0; j < M * H; ++j) acc += cx[j] * W_mh[(size_t)j * H + tid];
    qy[tid] = acc;
    __syncthreads();
    float acc2 = 0.f;
    for (int k = 0; k < H; ++k) acc2 += qy[k] * W_q2[(size_t)k * H + tid];
    q2[(size_t)b * H + tid] = acc2;
}

// ---------------- clip + mask + log_softmax ----------------
__global__ __launch_bounds__(128) void final_out_k(const float* __restrict__ u2,
                                                   const int* __restrict__ mask,
                                                   float* __restrict__ out) {
    int b = blockIdx.x;
    int tid = threadIdx.x;
    __shared__ float sv[N];
    __shared__ float mx_s, lse_s;
    if (tid < N) {
        float u = 10.f * tanhf(u2[(size_t)b * N + tid]);
        if (mask[(size_t)b * N + tid] > 0) u = NEG;
        sv[tid] = u;
    }
    __syncthreads();
    if (tid == 0) {
        float mx = -3e38f;
        for (int n = 0; n < N; ++n) mx = fmaxf(mx, sv[n]);
        float s = 0.f;
        for (int n = 0; n < N; ++n) s += __expf(sv[n] - mx);
        mx_s = mx;
        lse_s = logf(s);
    }
    __syncthreads();
    if (tid < N) out[(size_t)b * N + tid] = (sv[tid] - mx_s) - lse_s;
}

extern "C" void kernel_launch(void* const* d_in, const int* in_sizes, int n_in,
                              void* d_out, int out_size, void* d_ws, size_t ws_size,
                              hipStream_t stream) {
    const float* nf     = (const float*)d_in[0];
    const float* adj    = (const float*)d_in[1];
    const int*   mask   = (const int*)d_in[2];
    const float* W_emb  = (const float*)d_in[3];
    const float* W_rel  = (const float*)d_in[4];
    const float* W_self = (const float*)d_in[5];
    const float* Vec    = (const float*)d_in[6];
    const float* W_q    = (const float*)d_in[7];
    const float* W_ref  = (const float*)d_in[8];
    const float* W_mh   = (const float*)d_in[9];
    const float* Vec2   = (const float*)d_in[10];
    const float* W_q2   = (const float*)d_in[11];
    const float* W_ref2 = (const float*)d_in[12];
    const float* dec    = (const float*)d_in[13];
    const float* v_1    = (const float*)d_in[14];
    float* out = (float*)d_out;

    char* p = (char*)d_ws;
    size_t off = 0;
    auto alloc = [&](size_t bytes) -> char* {
        char* q = p + off;
        off += (bytes + 255) & ~(size_t)255;
        return q;
    };
    bf16* hA    = (bf16*)alloc((size_t)RT * H * sizeof(bf16));
    bf16* hB    = (bf16*)alloc((size_t)RT * H * sizeof(bf16));
    bf16* hT    = (bf16*)alloc((size_t)B * H * 128 * sizeof(bf16));
    bf16* msgb  = (bf16*)alloc((size_t)RT * 768 * sizeof(bf16));
    short* wtcat  = (short*)alloc(524288 * sizeof(short));
    short* wrefT  = (short*)alloc(262144 * sizeof(short));
    short* wref2T = (short*)alloc(65536 * sizeof(short));
    float* enc_mean = (float*)alloc((size_t)B * H * sizeof(float));
    float* qconst   = (float*)alloc((size_t)M * H * sizeof(float));
    float* vsumb    = (float*)alloc((size_t)M * H * sizeof(float));
    float* qbuf     = (float*)alloc((size_t)B * M * H * sizeof(float));
    float* scoresb  = (float*)alloc((size_t)B * M * N * sizeof(float));
    float* ctxb     = (float*)alloc((size_t)B * M * H * sizeof(float));
    float* q2b      = (float*)alloc((size_t)B * H * sizeof(float));
    float* u2b      = (float*)alloc((size_t)B * N * sizeof(float));

    wt_prep<<<3328, 256, 0, stream>>>(W_rel, W_self, W_ref, W_ref2, wtcat, wrefT, wref2T);
    embed_k<<<RT, 256, 0, stream>>>(nf, W_emb, hA);

    // hop 0
    transpose_h<<<B * 4, 256, 0, stream>>>(hA, hT);
    msg_mfma<<<dim3(B, E), 256, 0, stream>>>(adj, hT, msgb);
    hop_mfma<<<dim3(RT / 128, 2), 256, 0, stream>>>(msgb, hA, wtcat, hB);
    // hop 1
    transpose_h<<<B * 4, 256, 0, stream>>>(hB, hT);
    msg_mfma<<<dim3(B, E), 256, 0, stream>>>(adj, hT, msgb);
    hop_mfma<<<dim3(RT / 128, 2), 256, 0, stream>>>(msgb, hB, wtcat + 262144, hA);

    const bf16* enc = hA;

    mean_k<<<B, 256, 0, stream>>>(enc, enc_mean);
    prep_k<<<M, 256, 0, stream>>>(W_q, Vec, dec, v_1, qconst, vsumb);
    q_k<<<B * M, 256, 0, stream>>>(enc_mean, W_q, qconst, qbuf);
    head_mfma<<<dim3(RT / 64, M), 256, 0, stream>>>(enc, wrefT, qbuf, M * H, vsumb, scoresb, M * N);
    softmax_ctx_k<<<B * M, 256, 0, stream>>>(scoresb, mask, enc, ctxb);
    query2_k<<<B, 256, 0, stream>>>(ctxb, W_mh, W_q2, q2b);
    head_mfma<<<dim3(RT / 64, 1), 256, 0, stream>>>(enc, wref2T, q2b, H, Vec2, u2b, N);
    final_out_k<<<B, 128, 0, stream>>>(u2b, mask, out);
}

// Round 3
// 540.492 us; speedup vs baseline: 4.2802x; 1.1821x over previous
//
#include <hip/hip_runtime.h>
#include <hip/hip_bf16.h>

#define B 512
#define N 102
#define Pdim 12
#define H 256
#define M 4
#define E 3
#define NEG (-1e9f)
#define RT 52224   // B*N

typedef __hip_bfloat16 bf16;
typedef __attribute__((ext_vector_type(8))) short short8;
typedef __attribute__((ext_vector_type(4))) float f32x4;
typedef __attribute__((ext_vector_type(16))) float f32x16;

__device__ __forceinline__ float b2f(bf16 v) { return __bfloat162float(v); }
__device__ __forceinline__ bf16 f2b(float v) { return __float2bfloat16(v); }
__device__ __forceinline__ short f2bs(float v) {
    bf16 t = __float2bfloat16(v);
    return *reinterpret_cast<short*>(&t);
}
__device__ __forceinline__ float fast_tanh(float x) {
    float e = __expf(2.f * x);
    return 1.f - 2.f * __builtin_amdgcn_rcpf(e + 1.f);
}

// ---------------- weight prep: build bf16 transposed weights ----------------
// wtcat[hop][c][k] (k:1024 = 3*256 rel + 256 self), wrefT[(m*256+c)][k], wref2T[c][k],
// wmh_bf = bf16 copy of W_mh [1024][256], wq2_bf = bf16 copy of W_q2 [256][256]
__global__ __launch_bounds__(256) void wt_prep(const float* __restrict__ Wrel,
                                               const float* __restrict__ Wself,
                                               const float* __restrict__ Wref,
                                               const float* __restrict__ Wref2,
                                               const float* __restrict__ Wmh,
                                               const float* __restrict__ Wq2,
                                               short* __restrict__ wtcat,
                                               short* __restrict__ wrefT,
                                               short* __restrict__ wref2T,
                                               short* __restrict__ wmh_bf,
                                               short* __restrict__ wq2_bf) {
    int idx = blockIdx.x * 256 + threadIdx.x;
    if (idx < 524288) {
        int hop = idx >> 18;
        int r = idx & 262143;
        int c = r >> 10, k = r & 1023;
        float v;
        if (k < 768) {
            int e = k >> 8, h = k & 255;
            v = Wrel[(((size_t)hop * E + e) * H + h) * H + c];
        } else {
            int h = k - 768;
            v = Wself[((size_t)hop * H + h) * H + c];
        }
        wtcat[idx] = f2bs(v);
    } else if (idx < 786432) {
        int r = idx - 524288;            // (m*256+c)*256 + k
        int row = r >> 8, k = r & 255;
        int m = row >> 8, c = row & 255;
        wrefT[r] = f2bs(Wref[((size_t)m * H + k) * H + c]);
    } else if (idx < 851968) {
        int r = idx - 786432;
        int c = r >> 8, k = r & 255;
        wref2T[r] = f2bs(Wref2[k * H + c]);
    } else if (idx < 1114112) {
        int r = idx - 851968;
        wmh_bf[r] = f2bs(Wmh[r]);
    } else if (idx < 1179648) {
        int r = idx - 1114112;
        wq2_bf[r] = f2bs(Wq2[r]);
    }
}

// ---------------- K1: embedding h = nf @ W_emb ----------------
__global__ __launch_bounds__(256) void embed_k(const float* __restrict__ nf,
                                               const float* __restrict__ W_emb,
                                               bf16* __restrict__ h) {
    int row = blockIdx.x;
    int k = threadIdx.x;
    __shared__ float f[Pdim];
    if (k < Pdim) f[k] = nf[(size_t)row * Pdim + k];
    __syncthreads();
    float s = 0.f;
#pragma unroll
    for (int p = 0; p < Pdim; ++p) s += f[p] * W_emb[p * H + k];
    h[(size_t)row * H + k] = f2b(s);
}

// ---------------- transpose: hT[b][c][m] = h[b*N+m][c], zero-padded m>=102 ----------------
__global__ __launch_bounds__(256) void transpose_h(const bf16* __restrict__ h,
                                                   bf16* __restrict__ hT) {
    int b = blockIdx.x >> 2, cc = blockIdx.x & 3;
    int tid = threadIdx.x;
    __shared__ short ts[64 * 136];   // [c][m], m padded to 136 (valid 0..127, zero 102..127)
    // zero the pad region m in [102,128)
    for (int idx = tid; idx < 64 * 26; idx += 256) {
        int c = idx / 26, mm = 102 + idx % 26;
        ts[c * 136 + mm] = 0;
    }
    const short* hs = (const short*)h;
    for (int idx = tid; idx < 816; idx += 256) {    // 102 m * 8 short8-chunks
        int mm = idx >> 3, cj = (idx & 7) * 8;
        short8 v = *(const short8*)(hs + ((size_t)b * N + mm) * H + cc * 64 + cj);
#pragma unroll
        for (int j = 0; j < 8; ++j) ts[(cj + j) * 136 + mm] = v[j];
    }
    __syncthreads();
    short* ht = (short*)hT;
    for (int idx = tid; idx < 1024; idx += 256) {   // 64 c * 16 granules
        int c = idx >> 4, g = idx & 15;
        short8 v = *(const short8*)(&ts[c * 136 + g * 8]);
        *(short8*)(ht + ((size_t)b * H + cc * 64 + c) * 128 + g * 8) = v;
    }
}

// ---------------- msg MFMA: msg[b,n,e*256+c] = sum_m A[b,e,n,m] * h[b,m,c] ----------------
__global__ __launch_bounds__(256) void msg_mfma(const float* __restrict__ A,
                                                const bf16* __restrict__ hT,
                                                bf16* __restrict__ msgb) {
    int b = blockIdx.x, e = blockIdx.y;
    int tid = threadIdx.x;
    int w = tid >> 6, l = tid & 63;
    int cg = l & 15, rg = l >> 4;
    __shared__ short As[112 * 136];
    const float* Ab = A + (((size_t)b * E + e) * N) * N;
    for (int idx = tid; idx < 112 * 128; idx += 256) {
        int n = idx >> 7, m = idx & 127;
        float v = (n < N && m < N) ? Ab[n * N + m] : 0.f;
        As[n * 136 + m] = f2bs(v);
    }
    __syncthreads();

    f32x4 acc[7][4];
#pragma unroll
    for (int i = 0; i < 7; ++i)
#pragma unroll
        for (int j = 0; j < 4; ++j) acc[i][j] = (f32x4){0.f, 0.f, 0.f, 0.f};

    const short8* hT8 = (const short8*)hT;
#pragma unroll
    for (int step = 0; step < 4; ++step) {
        int m0 = step * 32;
        short8 bfr[4];
#pragma unroll
        for (int nt = 0; nt < 4; ++nt) {
            int col = w * 64 + nt * 16 + cg;
            bfr[nt] = hT8[((size_t)b * H + col) * 16 + (m0 >> 3) + rg];
        }
#pragma unroll
        for (int mt = 0; mt < 7; ++mt) {
            int n = mt * 16 + cg;
            short8 af = *(const short8*)(&As[n * 136 + m0 + rg * 8]);
#pragma unroll
            for (int nt = 0; nt < 4; ++nt)
                acc[mt][nt] = __builtin_amdgcn_mfma_f32_16x16x32_bf16(af, bfr[nt], acc[mt][nt], 0, 0, 0);
        }
    }
#pragma unroll
    for (int mt = 0; mt < 7; ++mt)
#pragma unroll
        for (int reg = 0; reg < 4; ++reg) {
            int n = mt * 16 + rg * 4 + reg;
            if (n < N) {
#pragma unroll
                for (int nt = 0; nt < 4; ++nt) {
                    int col = w * 64 + nt * 16 + cg;
                    msgb[((size_t)b * N + n) * 768 + e * H + col] = f2b(acc[mt][nt][reg]);
                }
            }
        }
}

// ------------- hop MFMA: hout = relu([msg|hin] @ Wcat),  X:[RT,1024], W^T:[256,1024] -------------
__global__ __launch_bounds__(256) void hop_mfma(const bf16* __restrict__ msgb,
                                                const bf16* __restrict__ hin,
                                                const short* __restrict__ wt,
                                                bf16* __restrict__ hout) {
    int rt = blockIdx.x, ct = blockIdx.y;
    int r0 = rt * 128, c0 = ct * 128;
    int tid = threadIdx.x;
    int w = tid >> 6, l = tid & 63;
    int wr = w >> 1, wc = w & 1;
    int cg = l & 15, rg = l >> 4;
    __shared__ short As[128 * 72];

    f32x4 acc[4][4];
#pragma unroll
    for (int i = 0; i < 4; ++i)
#pragma unroll
        for (int j = 0; j < 4; ++j) acc[i][j] = (f32x4){0.f, 0.f, 0.f, 0.f};

    const short8* wt8 = (const short8*)wt;
    const short* msgs = (const short*)msgb;
    const short* hins = (const short*)hin;

    for (int k0 = 0; k0 < 1024; k0 += 64) {
        __syncthreads();
#pragma unroll
        for (int i = 0; i < 4; ++i) {
            int cid = tid + i * 256;
            int n = cid >> 3, k8 = cid & 7;
            int row = r0 + n, kk = k0 + k8 * 8;
            const short* src = (kk < 768) ? (msgs + (size_t)row * 768 + kk)
                                          : (hins + (size_t)row * 256 + (kk - 768));
            *(short8*)(&As[n * 72 + k8 * 8]) = *(const short8*)src;
        }
        __syncthreads();
#pragma unroll
        for (int half = 0; half < 2; ++half) {
            int kk = half * 32;
            short8 bfr[4];
#pragma unroll
            for (int nt = 0; nt < 4; ++nt) {
                int c = c0 + wc * 64 + nt * 16 + cg;
                bfr[nt] = wt8[(size_t)c * 128 + ((k0 + kk) >> 3) + rg];
            }
#pragma unroll
            for (int mt = 0; mt < 4; ++mt) {
                int n = wr * 64 + mt * 16 + cg;
                short8 af = *(const short8*)(&As[n * 72 + kk + rg * 8]);
#pragma unroll
                for (int nt = 0; nt < 4; ++nt)
                    acc[mt][nt] = __builtin_amdgcn_mfma_f32_16x16x32_bf16(af, bfr[nt], acc[mt][nt], 0, 0, 0);
            }
        }
    }
#pragma unroll
    for (int mt = 0; mt < 4; ++mt)
#pragma unroll
        for (int reg = 0; reg < 4; ++reg) {
            int row = r0 + wr * 64 + mt * 16 + rg * 4 + reg;
#pragma unroll
            for (int nt = 0; nt < 4; ++nt) {
                int c = c0 + wc * 64 + nt * 16 + cg;
                float v = acc[mt][nt][reg];
                hout[(size_t)row * H + c] = f2b(v > 0.f ? v : 0.f);
            }
        }
}

// ------- head2: swapped-operand 32x32x16. D[c,r] = (W Xt); per-lane in-register c-reduction -------
// out[b, m*N + n] = sum_c fast_tanh(q[b, m*H+c] + (X W^T)[r,c]) * vs[m*H+c]
__global__ __launch_bounds__(256, 2) void head2_mfma(const bf16* __restrict__ X,
                                                     const short* __restrict__ WT,
                                                     const float* __restrict__ qb, int qbs,
                                                     const float* __restrict__ vsb,
                                                     float* __restrict__ outp, int obs) {
    int rt = blockIdx.x, m = blockIdx.y;
    int r0 = rt * 128;
    int tid = threadIdx.x;
    int w = tid >> 6, l = tid & 63;
    int lr = l & 31;     // output row selector (D-col) / W c-row lane index
    int lh = l >> 5;     // k-half selector
    __shared__ short Xs[128 * 256];     // 64KB, XOR-swizzled 16B granules
    __shared__ float qls[3 * 256];
    __shared__ float part[4][128];

    // stage X rows [r0, r0+128): granule id -> row id>>5, granule id&31; swizzle g ^= (r&7)
    const short* Xp = (const short*)X;
#pragma unroll
    for (int i = 0; i < 16; ++i) {
        int id = tid + i * 256;
        int r = id >> 5, g = id & 31;
        short8 v = *(const short8*)(Xp + (size_t)(r0 + r) * H + g * 8);
        *(short8*)((char*)Xs + r * 512 + ((g ^ (r & 7)) * 16)) = v;
    }
    // stage q rows for the (up to 3) batch indices this block touches
    int b_base = r0 / N;
#pragma unroll
    for (int i = 0; i < 3; ++i) {
        int bb = b_base + i;
        if (bb > B - 1) bb = B - 1;
        qls[i * 256 + tid] = qb[(size_t)bb * qbs + m * H + tid];
    }
    // W fragments held in registers: wave w owns c in [w*64, w*64+64) (2 c-tiles of 32)
    const short8* w8 = (const short8*)WT;
    int cbase = m * 256 + w * 64;
    short8 afr0[16], afr1[16];
#pragma unroll
    for (int ks = 0; ks < 16; ++ks) {
        afr0[ks] = w8[(size_t)(cbase + lr) * 32 + ks * 2 + lh];
        afr1[ks] = w8[(size_t)(cbase + 32 + lr) * 32 + ks * 2 + lh];
    }
    // vs for this wave's 32 c-values (c_local = (j&3)+8*(j>>2)+4*lh per tile)
    float vsl[32];
#pragma unroll
    for (int j = 0; j < 16; ++j) {
        int cl = (j & 3) + 8 * (j >> 2) + 4 * lh;
        vsl[j]      = vsb[m * H + w * 64 + cl];
        vsl[16 + j] = vsb[m * H + w * 64 + 32 + cl];
    }
    __syncthreads();

    int swz = lr & 7;
    for (int t = 0; t < 4; ++t) {
        f32x16 acc0, acc1;
#pragma unroll
        for (int j = 0; j < 16; ++j) { acc0[j] = 0.f; acc1[j] = 0.f; }
        const char* xbase = (const char*)Xs + (t * 32 + lr) * 512;
#pragma unroll
        for (int ks = 0; ks < 16; ++ks) {
            short8 bx = *(const short8*)(xbase + (((2 * ks + lh) ^ swz) * 16));
            acc0 = __builtin_amdgcn_mfma_f32_32x32x16_bf16(afr0[ks], bx, acc0, 0, 0, 0);
            acc1 = __builtin_amdgcn_mfma_f32_32x32x16_bf16(afr1[ks], bx, acc1, 0, 0, 0);
        }
        // in-lane epilogue: lane holds rows c (16 regs x 2 tiles) of ONE output row r
        int r = r0 + t * 32 + lr;
        int b = r / N;
        int boff = b - b_base;
        float s = 0.f;
#pragma unroll
        for (int j = 0; j < 16; ++j) {
            int cl = (j & 3) + 8 * (j >> 2) + 4 * lh;
            float x0 = qls[boff * 256 + w * 64 + cl] + acc0[j];
            s += fast_tanh(x0) * vsl[j];
            float x1 = qls[boff * 256 + w * 64 + 32 + cl] + acc1[j];
            s += fast_tanh(x1) * vsl[16 + j];
        }
        s += __shfl_xor(s, 32, 64);
        if (l < 32) part[w][t * 32 + lr] = s;
    }
    __syncthreads();
    if (tid < 128) {
        int r = r0 + tid;
        int b = r / N, n = r - b * N;
        outp[(size_t)b * obs + m * N + n] = part[0][tid] + part[1][tid] + part[2][tid] + part[3][tid];
    }
}

// ---------------- enc_mean ----------------
__global__ __launch_bounds__(256) void mean_k(const bf16* __restrict__ enc,
                                              float* __restrict__ enc_mean) {
    int b = blockIdx.x, k = threadIdx.x;
    float s = 0.f;
    for (int n = 0; n < N; ++n) s += b2f(enc[((size_t)b * N + n) * H + k]);
    enc_mean[(size_t)b * H + k] = s * (1.f / (float)N);
}

// ---------------- qconst[m,h], vsum[m,h] ----------------
__global__ __launch_bounds__(256) void prep_k(const float* __restrict__ W_q,
                                              const float* __restrict__ Vec,
                                              const float* __restrict__ dec,
                                              const float* __restrict__ v1,
                                              float* __restrict__ qconst,
                                              float* __restrict__ vsum) {
    int m = blockIdx.x, hh = threadIdx.x;
    __shared__ float dls[H], vls[H];
    dls[hh] = dec[hh];
    vls[hh] = v1[hh];
    __syncthreads();
    const float* Wm = W_q + (size_t)m * (3 * H) * H;
    float s = 0.f;
    for (int f = 0; f < H; ++f)
        s += dls[f] * Wm[(H + f) * H + hh] + vls[f] * Wm[(2 * H + f) * H + hh];
    qconst[m * H + hh] = s;
    float vs = 0.f;
    const float* Vr = Vec + ((size_t)m * H + hh) * H;
    for (int k = 0; k < H; ++k) vs += Vr[k];
    vsum[m * H + hh] = vs;
}

// ---------------- q[b,m,h] ----------------
__global__ __launch_bounds__(256) void q_k(const float* __restrict__ enc_mean,
                                           const float* __restrict__ W_q,
                                           const float* __restrict__ qconst,
                                           float* __restrict__ qbuf) {
    int bid = blockIdx.x;
    int b = bid >> 2, m = bid & 3;
    int hh = threadIdx.x;
    __shared__ float em[H];
    em[hh] = enc_mean[(size_t)b * H + hh];
    __syncthreads();
    const float* Wm = W_q + (size_t)m * (3 * H) * H;
    float s = qconst[m * H + hh];
    for (int f = 0; f < H; ++f) s += em[f] * Wm[f * H + hh];
    qbuf[((size_t)b * M + m) * H + hh] = s;
}

// ---------------- masked softmax + ctx (wave-parallel reductions) ----------------
__global__ __launch_bounds__(256) void softmax_ctx_k(const float* __restrict__ scores,
                                                     const int* __restrict__ mask,
                                                     const bf16* __restrict__ enc,
                                                     float* __restrict__ ctx) {
    int bid = blockIdx.x;
    int b = bid >> 2, m = bid & 3;
    int tid = threadIdx.x;
    __shared__ float a[128];
    __shared__ float red[2];
    float sv = NEG;
    if (tid < N)
        sv = (mask[(size_t)b * N + tid] > 0) ? NEG : scores[((size_t)b * M + m) * N + tid];
    if (tid < 128) a[tid] = sv;
    __syncthreads();
    if (tid < 64) {
        float v = fmaxf(a[tid], a[tid + 64]);
        v = fmaxf(v, __shfl_xor(v, 32, 64));
        v = fmaxf(v, __shfl_xor(v, 16, 64));
        v = fmaxf(v, __shfl_xor(v, 8, 64));
        v = fmaxf(v, __shfl_xor(v, 4, 64));
        v = fmaxf(v, __shfl_xor(v, 2, 64));
        v = fmaxf(v, __shfl_xor(v, 1, 64));
        if (tid == 0) red[0] = v;
    }
    __syncthreads();
    float mx = red[0];
    float ev = (tid < N) ? __expf(sv - mx) : 0.f;
    if (tid < 128) a[tid] = ev;
    __syncthreads();
    if (tid < 64) {
        float v = a[tid] + a[tid + 64];
        v += __shfl_xor(v, 32, 64);
        v += __shfl_xor(v, 16, 64);
        v += __shfl_xor(v, 8, 64);
        v += __shfl_xor(v, 4, 64);
        v += __shfl_xor(v, 2, 64);
        v += __shfl_xor(v, 1, 64);
        if (tid == 0) red[1] = __builtin_amdgcn_rcpf(v);
    }
    __syncthreads();
    float inv = red[1];
    float c = 0.f;
    for (int n = 0; n < N; ++n)
        c += a[n] * b2f(enc[((size_t)b * N + n) * H + tid]);
    ctx[((size_t)b * M + m) * H + tid] = c * inv;
}

// ---------------- query2 = (ctx @ W_mh) @ W_q2 (bf16 weights) ----------------
__global__ __launch_bounds__(256) void query2_k(const float* __restrict__ ctx,
                                                const short* __restrict__ wmh,
                                                const short* __restrict__ wq2,
                                                float* __restrict__ q2) {
    int b = blockIdx.x;
    int tid = threadIdx.x;
    __shared__ float cx[M * H];
    __shared__ float qy[H];
    for (int idx = tid; idx < M * H; idx += 256) cx[idx] = ctx[(size_t)b * M * H + idx];
    __syncthreads();
    const bf16* wm = (const bf16*)wmh;
    float acc = 0.f;
    for (int j = 0; j < M * H; ++j) acc += cx[j] * b2f(wm[(size_t)j * H + tid]);
    qy[tid] = acc;
    __syncthreads();
    const bf16* w2 = (const bf16*)wq2;
    float acc2 = 0.f;
    for (int k = 0; k < H; ++k) acc2 += qy[k] * b2f(w2[(size_t)k * H + tid]);
    q2[(size_t)b * H + tid] = acc2;
}

// ---------------- clip + mask + log_softmax ----------------
__global__ __launch_bounds__(128) void final_out_k(const float* __restrict__ u2,
                                                   const int* __restrict__ mask,
                                                   float* __restrict__ out) {
    int b = blockIdx.x;
    int tid = threadIdx.x;
    __shared__ float sv[N];
    __shared__ float mx_s, lse_s;
    if (tid < N) {
        float u = 10.f * tanhf(u2[(size_t)b * N + tid]);
        if (mask[(size_t)b * N + tid] > 0) u = NEG;
        sv[tid] = u;
    }
    __syncthreads();
    if (tid == 0) {
        float mx = -3e38f;
        for (int n = 0; n < N; ++n) mx = fmaxf(mx, sv[n]);
        float s = 0.f;
        for (int n = 0; n < N; ++n) s += __expf(sv[n] - mx);
        mx_s = mx;
        lse_s = logf(s);
    }
    __syncthreads();
    if (tid < N) out[(size_t)b * N + tid] = (sv[tid] - mx_s) - lse_s;
}

extern "C" void kernel_launch(void* const* d_in, const int* in_sizes, int n_in,
                              void* d_out, int out_size, void* d_ws, size_t ws_size,
                              hipStream_t stream) {
    const float* nf     = (const float*)d_in[0];
    const float* adj    = (const float*)d_in[1];
    const int*   mask   = (const int*)d_in[2];
    const float* W_emb  = (const float*)d_in[3];
    const float* W_rel  = (const float*)d_in[4];
    const float* W_self = (const float*)d_in[5];
    const float* Vec    = (const float*)d_in[6];
    const float* W_q    = (const float*)d_in[7];
    const float* W_ref  = (const float*)d_in[8];
    const float* W_mh   = (const float*)d_in[9];
    const float* Vec2   = (const float*)d_in[10];
    const float* W_q2   = (const float*)d_in[11];
    const float* W_ref2 = (const float*)d_in[12];
    const float* dec    = (const float*)d_in[13];
    const float* v_1    = (const float*)d_in[14];
    float* out = (float*)d_out;

    char* p = (char*)d_ws;
    size_t off = 0;
    auto alloc = [&](size_t bytes) -> char* {
        char* q = p + off;
        off += (bytes + 255) & ~(size_t)255;
        return q;
    };
    bf16* hA    = (bf16*)alloc((size_t)RT * H * sizeof(bf16));
    bf16* hB    = (bf16*)alloc((size_t)RT * H * sizeof(bf16));
    bf16* hT    = (bf16*)alloc((size_t)B * H * 128 * sizeof(bf16));
    bf16* msgb  = (bf16*)alloc((size_t)RT * 768 * sizeof(bf16));
    short* wtcat  = (short*)alloc(524288 * sizeof(short));
    short* wrefT  = (short*)alloc(262144 * sizeof(short));
    short* wref2T = (short*)alloc(65536 * sizeof(short));
    short* wmh_bf = (short*)alloc(262144 * sizeof(short));
    short* wq2_bf = (short*)alloc(65536 * sizeof(short));
    float* enc_mean = (float*)alloc((size_t)B * H * sizeof(float));
    float* qconst   = (float*)alloc((size_t)M * H * sizeof(float));
    float* vsumb    = (float*)alloc((size_t)M * H * sizeof(float));
    float* qbuf     = (float*)alloc((size_t)B * M * H * sizeof(float));
    float* scoresb  = (float*)alloc((size_t)B * M * N * sizeof(float));
    float* ctxb     = (float*)alloc((size_t)B * M * H * sizeof(float));
    float* q2b      = (float*)alloc((size_t)B * H * sizeof(float));
    float* u2b      = (float*)alloc((size_t)B * N * sizeof(float));

    wt_prep<<<4608, 256, 0, stream>>>(W_rel, W_self, W_ref, W_ref2, W_mh, W_q2,
                                      wtcat, wrefT, wref2T, wmh_bf, wq2_bf);
    embed_k<<<RT, 256, 0, stream>>>(nf, W_emb, hA);

    // hop 0
    transpose_h<<<B * 4, 256, 0, stream>>>(hA, hT);
    msg_mfma<<<dim3(B, E), 256, 0, stream>>>(adj, hT, msgb);
    hop_mfma<<<dim3(RT / 128, 2), 256, 0, stream>>>(msgb, hA, wtcat, hB);
    // hop 1
    transpose_h<<<B * 4, 256, 0, stream>>>(hB, hT);
    msg_mfma<<<dim3(B, E), 256, 0, stream>>>(adj, hT, msgb);
    hop_mfma<<<dim3(RT / 128, 2), 256, 0, stream>>>(msgb, hB, wtcat + 262144, hA);

    const bf16* enc = hA;

    mean_k<<<B, 256, 0, stream>>>(enc, enc_mean);
    prep_k<<<M, 256, 0, stream>>>(W_q, Vec, dec, v_1, qconst, vsumb);
    q_k<<<B * M, 256, 0, stream>>>(enc_mean, W_q, qconst, qbuf);
    head2_mfma<<<dim3(RT / 128, M), 256, 0, stream>>>(enc, wrefT, qbuf, M * H, vsumb, scoresb, M * N);
    softmax_ctx_k<<<B * M, 256, 0, stream>>>(scoresb, mask, enc, ctxb);
    query2_k<<<B, 256, 0, stream>>>(ctxb, wmh_bf, wq2_bf, q2b);
    head2_mfma<<<dim3(RT / 128, 1), 256, 0, stream>>>(enc, wref2T, q2b, H, Vec2, u2b, N);
    final_out_k<<<B, 128, 0, stream>>>(u2b, mask, out);
}

// Round 4
// 317.649 us; speedup vs baseline: 7.2830x; 1.7015x over previous
//
#include <hip/hip_runtime.h>
#include <hip/hip_bf16.h>

#define B 512
#define N 102
#define Pdim 12
#define H 256
#define M 4
#define E 3
#define NEG (-1e9f)
#define RT 52224   // B*N

typedef __hip_bfloat16 bf16;
typedef __attribute__((ext_vector_type(8))) short short8;
typedef __attribute__((ext_vector_type(4))) float f32x4;
typedef __attribute__((ext_vector_type(16))) float f32x16;

__device__ __forceinline__ float b2f(bf16 v) { return __bfloat162float(v); }
__device__ __forceinline__ bf16 f2b(float v) { return __float2bfloat16(v); }
__device__ __forceinline__ short f2bs(float v) {
    bf16 t = __float2bfloat16(v);
    return *reinterpret_cast<short*>(&t);
}
__device__ __forceinline__ float fast_tanh(float x) {
    float e = __expf(2.f * x);
    return 1.f - 2.f * __builtin_amdgcn_rcpf(e + 1.f);
}

// ---------------- weight prep ----------------
// wfrag: fragment-ordered [hop][ct:16][ks:32][lane:64][j:8] of wtcat_logical[c:256][k:1024]
//   (k<768: W_rel[e=k>>8][k&255][c]; k>=768: W_self[k-768][c])
//   c = ct*16 + (lane&15); k = ks*32 + ((lane>>4)&3)*8 + j
// wrefT[(m*256+c)][k], wref2T[c][k], wmh_bf, wq2_bf as before.
__global__ __launch_bounds__(256) void wt_prep(const float* __restrict__ Wrel,
                                               const float* __restrict__ Wself,
                                               const float* __restrict__ Wref,
                                               const float* __restrict__ Wref2,
                                               const float* __restrict__ Wmh,
                                               const float* __restrict__ Wq2,
                                               short* __restrict__ wfrag,
                                               short* __restrict__ wrefT,
                                               short* __restrict__ wref2T,
                                               short* __restrict__ wmh_bf,
                                               short* __restrict__ wq2_bf) {
    int idx = blockIdx.x * 256 + threadIdx.x;
    if (idx < 524288) {
        int j = idx & 7;
        int lq = (idx >> 3) & 63;
        int ks = (idx >> 9) & 31;
        int ct = (idx >> 14) & 15;
        int hop = idx >> 18;
        int c = ct * 16 + (lq & 15);
        int k = ks * 32 + ((lq >> 4) & 3) * 8 + j;
        float v;
        if (k < 768) {
            int e = k >> 8, kk = k & 255;
            v = Wrel[(((size_t)hop * E + e) * H + kk) * H + c];
        } else {
            v = Wself[((size_t)hop * H + (k - 768)) * H + c];
        }
        wfrag[idx] = f2bs(v);
    } else if (idx < 786432) {
        int r = idx - 524288;            // (m*256+c)*256 + k
        int row = r >> 8, k = r & 255;
        int m = row >> 8, c = row & 255;
        wrefT[r] = f2bs(Wref[((size_t)m * H + k) * H + c]);
    } else if (idx < 851968) {
        int r = idx - 786432;
        int c = r >> 8, k = r & 255;
        wref2T[r] = f2bs(Wref2[k * H + c]);
    } else if (idx < 1114112) {
        int r = idx - 851968;
        wmh_bf[r] = f2bs(Wmh[r]);
    } else if (idx < 1179648) {
        int r = idx - 1114112;
        wq2_bf[r] = f2bs(Wq2[r]);
    }
}

// ---------------- K1: embedding h = nf @ W_emb ----------------
__global__ __launch_bounds__(256) void embed_k(const float* __restrict__ nf,
                                               const float* __restrict__ W_emb,
                                               bf16* __restrict__ h) {
    int row = blockIdx.x;
    int k = threadIdx.x;
    __shared__ float f[Pdim];
    if (k < Pdim) f[k] = nf[(size_t)row * Pdim + k];
    __syncthreads();
    float s = 0.f;
#pragma unroll
    for (int p = 0; p < Pdim; ++p) s += f[p] * W_emb[p * H + k];
    h[(size_t)row * H + k] = f2b(s);
}

// ------------- fused hop: h_next = relu( sum_e A_e (h Wrel[e]) + h Wself ) -------------
// One block per batch b. 512 threads = 8 waves. Gather-last (associativity reorder).
// LDS: hS [112][264] (59136B) + YtS [256][136] (69632B) + AsS [112][136] (30464B) = 155.5KB
#define HP 264     // h LDS pitch (shorts): 528B = 16B-mult, 2-way banks
#define YP 136     // Yt/As pitch (shorts): 272B = 16B-mult, 2-way banks
__global__ __launch_bounds__(512) void hop_fused(const bf16* __restrict__ hin,
                                                 const float* __restrict__ adj,
                                                 const short* __restrict__ wfragp,
                                                 bf16* __restrict__ hout) {
    int b = blockIdx.x;
    int tid = threadIdx.x;
    int w = tid >> 6;          // wave 0..7; owns c in [32w, 32w+32)
    int l = tid & 63;
    int cg = l & 15;
    int rg = (l >> 4) & 3;

    __shared__ short hS[112 * HP];
    __shared__ short YtS[256 * YP];
    __shared__ short AsS[112 * YP];

    const short8 z8 = {0, 0, 0, 0, 0, 0, 0, 0};
    // zero-fill: AsS fully; hS rows [102,112); YtS cols [112,128)
    for (int i = tid; i < (112 * YP) / 8; i += 512) ((short8*)AsS)[i] = z8;
    for (int i = tid; i < 10 * 32; i += 512) {
        int n = 102 + (i >> 5), g = i & 31;
        *(short8*)(&hS[n * HP + g * 8]) = z8;
    }
    for (int i = tid; i < 512; i += 512) {
        int c = i >> 1, part = i & 1;
        *(short8*)(&YtS[c * YP + 112 + part * 8]) = z8;
    }
    // stage h[b] rows [0,102)
    const short* hp = (const short*)hin;
    for (int i = tid; i < 102 * 32; i += 512) {
        int n = i >> 5, g = i & 31;
        *(short8*)(&hS[n * HP + g * 8]) = *(const short8*)(hp + ((size_t)b * N + n) * H + g * 8);
    }
    __syncthreads();

    const short8* wf8 = (const short8*)wfragp;
    int ct0 = 2 * w, ct1 = 2 * w + 1;

    f32x4 hacc[2][7];
#pragma unroll
    for (int i = 0; i < 2; ++i)
#pragma unroll
        for (int j = 0; j < 7; ++j) hacc[i][j] = (f32x4){0.f, 0.f, 0.f, 0.f};

    for (int e = 0; e < E; ++e) {
        // stage A_e interior (f32 -> bf16)
        const float* Ab = adj + (((size_t)b * E + e) * N) * N;
        for (int i = tid; i < N * N; i += 512) {
            int n = i / N, m = i - n * N;
            AsS[n * YP + m] = f2bs(Ab[i]);
        }
        // G: Ye^T[c][m] = sum_k WrelT[c][k] h[m][k]  (wave: c in 2 ct-tiles, m in 7 tiles)
        f32x4 g[2][7];
#pragma unroll
        for (int i = 0; i < 2; ++i)
#pragma unroll
            for (int j = 0; j < 7; ++j) g[i][j] = (f32x4){0.f, 0.f, 0.f, 0.f};
#pragma unroll
        for (int ks = 0; ks < 8; ++ks) {
            short8 wfa = wf8[(ct0 * 32 + e * 8 + ks) * 64 + l];
            short8 wfb = wf8[(ct1 * 32 + e * 8 + ks) * 64 + l];
#pragma unroll
            for (int mt = 0; mt < 7; ++mt) {
                short8 hf = *(const short8*)(&hS[(mt * 16 + cg) * HP + ks * 32 + rg * 8]);
                g[0][mt] = __builtin_amdgcn_mfma_f32_16x16x32_bf16(wfa, hf, g[0][mt], 0, 0, 0);
                g[1][mt] = __builtin_amdgcn_mfma_f32_16x16x32_bf16(wfb, hf, g[1][mt], 0, 0, 0);
            }
        }
        // write Ye^T to LDS (D: row=c=ct*16+rg*4+r, col=m=mt*16+cg)
#pragma unroll
        for (int ctl = 0; ctl < 2; ++ctl)
#pragma unroll
            for (int mt = 0; mt < 7; ++mt)
#pragma unroll
                for (int r = 0; r < 4; ++r) {
                    int c = (2 * w + ctl) * 16 + rg * 4 + r;
                    YtS[c * YP + mt * 16 + cg] = f2bs(g[ctl][mt][r]);
                }
        __syncthreads();
        // gather: hacc[n][c] += sum_m As[n][m] * Yt[c][m]
#pragma unroll
        for (int ks = 0; ks < 4; ++ks) {
            short8 yf0 = *(const short8*)(&YtS[(ct0 * 16 + cg) * YP + ks * 32 + rg * 8]);
            short8 yf1 = *(const short8*)(&YtS[(ct1 * 16 + cg) * YP + ks * 32 + rg * 8]);
#pragma unroll
            for (int nt = 0; nt < 7; ++nt) {
                short8 af = *(const short8*)(&AsS[(nt * 16 + cg) * YP + ks * 32 + rg * 8]);
                hacc[0][nt] = __builtin_amdgcn_mfma_f32_16x16x32_bf16(af, yf0, hacc[0][nt], 0, 0, 0);
                hacc[1][nt] = __builtin_amdgcn_mfma_f32_16x16x32_bf16(af, yf1, hacc[1][nt], 0, 0, 0);
            }
        }
        __syncthreads();
    }
    // self: hacc[n][c] += sum_k h[n][k] Wself[k][c]   (wfrag ks offset 24)
#pragma unroll
    for (int ks = 0; ks < 8; ++ks) {
        short8 wfa = wf8[(ct0 * 32 + 24 + ks) * 64 + l];
        short8 wfb = wf8[(ct1 * 32 + 24 + ks) * 64 + l];
#pragma unroll
        for (int nt = 0; nt < 7; ++nt) {
            short8 hf = *(const short8*)(&hS[(nt * 16 + cg) * HP + ks * 32 + rg * 8]);
            hacc[0][nt] = __builtin_amdgcn_mfma_f32_16x16x32_bf16(hf, wfa, hacc[0][nt], 0, 0, 0);
            hacc[1][nt] = __builtin_amdgcn_mfma_f32_16x16x32_bf16(hf, wfb, hacc[1][nt], 0, 0, 0);
        }
    }
    __syncthreads();   // all reads of hS done; reuse as output staging
    // relu + pack into hS[n][c]
#pragma unroll
    for (int ctl = 0; ctl < 2; ++ctl)
#pragma unroll
        for (int nt = 0; nt < 7; ++nt)
#pragma unroll
            for (int r = 0; r < 4; ++r) {
                int n = nt * 16 + rg * 4 + r;
                int c = w * 32 + ctl * 16 + cg;
                float v = hacc[ctl][nt][r];
                hS[n * HP + c] = f2bs(v > 0.f ? v : 0.f);
            }
    __syncthreads();
    short* ho = (short*)hout;
    for (int i = tid; i < 102 * 32; i += 512) {
        int n = i >> 5, g = i & 31;
        *(short8*)(ho + ((size_t)b * N + n) * H + g * 8) = *(const short8*)(&hS[n * HP + g * 8]);
    }
}

// ------- head2: swapped-operand 32x32x16. per-lane in-register c-reduction -------
__global__ __launch_bounds__(256, 2) void head2_mfma(const bf16* __restrict__ X,
                                                     const short* __restrict__ WT,
                                                     const float* __restrict__ qb, int qbs,
                                                     const float* __restrict__ vsb,
                                                     float* __restrict__ outp, int obs) {
    int rt = blockIdx.x, m = blockIdx.y;
    int r0 = rt * 128;
    int tid = threadIdx.x;
    int w = tid >> 6, l = tid & 63;
    int lr = l & 31;
    int lh = l >> 5;
    __shared__ short Xs[128 * 256];
    __shared__ float qls[3 * 256];
    __shared__ float part[4][128];

    const short* Xp = (const short*)X;
#pragma unroll
    for (int i = 0; i < 16; ++i) {
        int id = tid + i * 256;
        int r = id >> 5, g = id & 31;
        short8 v = *(const short8*)(Xp + (size_t)(r0 + r) * H + g * 8);
        *(short8*)((char*)Xs + r * 512 + ((g ^ (r & 7)) * 16)) = v;
    }
    int b_base = r0 / N;
#pragma unroll
    for (int i = 0; i < 3; ++i) {
        int bb = b_base + i;
        if (bb > B - 1) bb = B - 1;
        qls[i * 256 + tid] = qb[(size_t)bb * qbs + m * H + tid];
    }
    const short8* w8 = (const short8*)WT;
    int cbase = m * 256 + w * 64;
    short8 afr0[16], afr1[16];
#pragma unroll
    for (int ks = 0; ks < 16; ++ks) {
        afr0[ks] = w8[(size_t)(cbase + lr) * 32 + ks * 2 + lh];
        afr1[ks] = w8[(size_t)(cbase + 32 + lr) * 32 + ks * 2 + lh];
    }
    float vsl[32];
#pragma unroll
    for (int j = 0; j < 16; ++j) {
        int cl = (j & 3) + 8 * (j >> 2) + 4 * lh;
        vsl[j]      = vsb[m * H + w * 64 + cl];
        vsl[16 + j] = vsb[m * H + w * 64 + 32 + cl];
    }
    __syncthreads();

    int swz = lr & 7;
    for (int t = 0; t < 4; ++t) {
        f32x16 acc0, acc1;
#pragma unroll
        for (int j = 0; j < 16; ++j) { acc0[j] = 0.f; acc1[j] = 0.f; }
        const char* xbase = (const char*)Xs + (t * 32 + lr) * 512;
#pragma unroll
        for (int ks = 0; ks < 16; ++ks) {
            short8 bx = *(const short8*)(xbase + (((2 * ks + lh) ^ swz) * 16));
            acc0 = __builtin_amdgcn_mfma_f32_32x32x16_bf16(afr0[ks], bx, acc0, 0, 0, 0);
            acc1 = __builtin_amdgcn_mfma_f32_32x32x16_bf16(afr1[ks], bx, acc1, 0, 0, 0);
        }
        int r = r0 + t * 32 + lr;
        int b = r / N;
        int boff = b - b_base;
        float s = 0.f;
#pragma unroll
        for (int j = 0; j < 16; ++j) {
            int cl = (j & 3) + 8 * (j >> 2) + 4 * lh;
            float x0 = qls[boff * 256 + w * 64 + cl] + acc0[j];
            s += fast_tanh(x0) * vsl[j];
            float x1 = qls[boff * 256 + w * 64 + 32 + cl] + acc1[j];
            s += fast_tanh(x1) * vsl[16 + j];
        }
        s += __shfl_xor(s, 32, 64);
        if (l < 32) part[w][t * 32 + lr] = s;
    }
    __syncthreads();
    if (tid < 128) {
        int r = r0 + tid;
        int b = r / N, n = r - b * N;
        outp[(size_t)b * obs + m * N + n] = part[0][tid] + part[1][tid] + part[2][tid] + part[3][tid];
    }
}

// ---------------- enc_mean ----------------
__global__ __launch_bounds__(256) void mean_k(const bf16* __restrict__ enc,
                                              float* __restrict__ enc_mean) {
    int b = blockIdx.x, k = threadIdx.x;
    float s = 0.f;
    for (int n = 0; n < N; ++n) s += b2f(enc[((size_t)b * N + n) * H + k]);
    enc_mean[(size_t)b * H + k] = s * (1.f / (float)N);
}

// ---------------- qconst[m,h], vsum[m,h] ----------------
__global__ __launch_bounds__(256) void prep_k(const float* __restrict__ W_q,
                                              const float* __restrict__ Vec,
                                              const float* __restrict__ dec,
                                              const float* __restrict__ v1,
                                              float* __restrict__ qconst,
                                              float* __restrict__ vsum) {
    int m = blockIdx.x, hh = threadIdx.x;
    __shared__ float dls[H], vls[H];
    dls[hh] = dec[hh];
    vls[hh] = v1[hh];
    __syncthreads();
    const float* Wm = W_q + (size_t)m * (3 * H) * H;
    float s = 0.f;
    for (int f = 0; f < H; ++f)
        s += dls[f] * Wm[(H + f) * H + hh] + vls[f] * Wm[(2 * H + f) * H + hh];
    qconst[m * H + hh] = s;
    float vs = 0.f;
    const float* Vr = Vec + ((size_t)m * H + hh) * H;
    for (int k = 0; k < H; ++k) vs += Vr[k];
    vsum[m * H + hh] = vs;
}

// ---------------- q[b,m,h] ----------------
__global__ __launch_bounds__(256) void q_k(const float* __restrict__ enc_mean,
                                           const float* __restrict__ W_q,
                                           const float* __restrict__ qconst,
                                           float* __restrict__ qbuf) {
    int bid = blockIdx.x;
    int b = bid >> 2, m = bid & 3;
    int hh = threadIdx.x;
    __shared__ float em[H];
    em[hh] = enc_mean[(size_t)b * H + hh];
    __syncthreads();
    const float* Wm = W_q + (size_t)m * (3 * H) * H;
    float s = qconst[m * H + hh];
    for (int f = 0; f < H; ++f) s += em[f] * Wm[f * H + hh];
    qbuf[((size_t)b * M + m) * H + hh] = s;
}

// ---------------- masked softmax + ctx (wave-parallel reductions) ----------------
__global__ __launch_bounds__(256) void softmax_ctx_k(const float* __restrict__ scores,
                                                     const int* __restrict__ mask,
                                                     const bf16* __restrict__ enc,
                                                     float* __restrict__ ctx) {
    int bid = blockIdx.x;
    int b = bid >> 2, m = bid & 3;
    int tid = threadIdx.x;
    __shared__ float a[128];
    __shared__ float red[2];
    float sv = NEG;
    if (tid < N)
        sv = (mask[(size_t)b * N + tid] > 0) ? NEG : scores[((size_t)b * M + m) * N + tid];
    if (tid < 128) a[tid] = sv;
    __syncthreads();
    if (tid < 64) {
        float v = fmaxf(a[tid], a[tid + 64]);
        v = fmaxf(v, __shfl_xor(v, 32, 64));
        v = fmaxf(v, __shfl_xor(v, 16, 64));
        v = fmaxf(v, __shfl_xor(v, 8, 64));
        v = fmaxf(v, __shfl_xor(v, 4, 64));
        v = fmaxf(v, __shfl_xor(v, 2, 64));
        v = fmaxf(v, __shfl_xor(v, 1, 64));
        if (tid == 0) red[0] = v;
    }
    __syncthreads();
    float mx = red[0];
    float ev = (tid < N) ? __expf(sv - mx) : 0.f;
    if (tid < 128) a[tid] = ev;
    __syncthreads();
    if (tid < 64) {
        float v = a[tid] + a[tid + 64];
        v += __shfl_xor(v, 32, 64);
        v += __shfl_xor(v, 16, 64);
        v += __shfl_xor(v, 8, 64);
        v += __shfl_xor(v, 4, 64);
        v += __shfl_xor(v, 2, 64);
        v += __shfl_xor(v, 1, 64);
        if (tid == 0) red[1] = __builtin_amdgcn_rcpf(v);
    }
    __syncthreads();
    float inv = red[1];
    float c = 0.f;
    for (int n = 0; n < N; ++n)
        c += a[n] * b2f(enc[((size_t)b * N + n) * H + tid]);
    ctx[((size_t)b * M + m) * H + tid] = c * inv;
}

// ---------------- query2 = (ctx @ W_mh) @ W_q2 (bf16 weights) ----------------
__global__ __launch_bounds__(256) void query2_k(const float* __restrict__ ctx,
                                                const short* __restrict__ wmh,
                                                const short* __restrict__ wq2,
                                                float* __restrict__ q2) {
    int b = blockIdx.x;
    int tid = threadIdx.x;
    __shared__ float cx[M * H];
    __shared__ float qy[H];
    for (int idx = tid; idx < M * H; idx += 256) cx[idx] = ctx[(size_t)b * M * H + idx];
    __syncthreads();
    const bf16* wm = (const bf16*)wmh;
    float acc = 0.f;
    for (int j = 0; j < M * H; ++j) acc += cx[j] * b2f(wm[(size_t)j * H + tid]);
    qy[tid] = acc;
    __syncthreads();
    const bf16* w2 = (const bf16*)wq2;
    float acc2 = 0.f;
    for (int k = 0; k < H; ++k) acc2 += qy[k] * b2f(w2[(size_t)k * H + tid]);
    q2[(size_t)b * H + tid] = acc2;
}

// ---------------- clip + mask + log_softmax ----------------
__global__ __launch_bounds__(128) void final_out_k(const float* __restrict__ u2,
                                                   const int* __restrict__ mask,
                                                   float* __restrict__ out) {
    int b = blockIdx.x;
    int tid = threadIdx.x;
    __shared__ float sv[N];
    __shared__ float mx_s, lse_s;
    if (tid < N) {
        float u = 10.f * tanhf(u2[(size_t)b * N + tid]);
        if (mask[(size_t)b * N + tid] > 0) u = NEG;
        sv[tid] = u;
    }
    __syncthreads();
    if (tid == 0) {
        float mx = -3e38f;
        for (int n = 0; n < N; ++n) mx = fmaxf(mx, sv[n]);
        float s = 0.f;
        for (int n = 0; n < N; ++n) s += __expf(sv[n] - mx);
        mx_s = mx;
        lse_s = logf(s);
    }
    __syncthreads();
    if (tid < N) out[(size_t)b * N + tid] = (sv[tid] - mx_s) - lse_s;
}

extern "C" void kernel_launch(void* const* d_in, const int* in_sizes, int n_in,
                              void* d_out, int out_size, void* d_ws, size_t ws_size,
                              hipStream_t stream) {
    const float* nf     = (const float*)d_in[0];
    const float* adj    = (const float*)d_in[1];
    const int*   mask   = (const int*)d_in[2];
    const float* W_emb  = (const float*)d_in[3];
    const float* W_rel  = (const float*)d_in[4];
    const float* W_self = (const float*)d_in[5];
    const float* Vec    = (const float*)d_in[6];
    const float* W_q    = (const float*)d_in[7];
    const float* W_ref  = (const float*)d_in[8];
    const float* W_mh   = (const float*)d_in[9];
    const float* Vec2   = (const float*)d_in[10];
    const float* W_q2   = (const float*)d_in[11];
    const float* W_ref2 = (const float*)d_in[12];
    const float* dec    = (const float*)d_in[13];
    const float* v_1    = (const float*)d_in[14];
    float* out = (float*)d_out;

    char* p = (char*)d_ws;
    size_t off = 0;
    auto alloc = [&](size_t bytes) -> char* {
        char* q = p + off;
        off += (bytes + 255) & ~(size_t)255;
        return q;
    };
    bf16* hA    = (bf16*)alloc((size_t)RT * H * sizeof(bf16));
    bf16* hB    = (bf16*)alloc((size_t)RT * H * sizeof(bf16));
    short* wfrag  = (short*)alloc(524288 * sizeof(short));
    short* wrefT  = (short*)alloc(262144 * sizeof(short));
    short* wref2T = (short*)alloc(65536 * sizeof(short));
    short* wmh_bf = (short*)alloc(262144 * sizeof(short));
    short* wq2_bf = (short*)alloc(65536 * sizeof(short));
    float* enc_mean = (float*)alloc((size_t)B * H * sizeof(float));
    float* qconst   = (float*)alloc((size_t)M * H * sizeof(float));
    float* vsumb    = (float*)alloc((size_t)M * H * sizeof(float));
    float* qbuf     = (float*)alloc((size_t)B * M * H * sizeof(float));
    float* scoresb  = (float*)alloc((size_t)B * M * N * sizeof(float));
    float* ctxb     = (float*)alloc((size_t)B * M * H * sizeof(float));
    float* q2b      = (float*)alloc((size_t)B * H * sizeof(float));
    float* u2b      = (float*)alloc((size_t)B * N * sizeof(float));

    wt_prep<<<4608, 256, 0, stream>>>(W_rel, W_self, W_ref, W_ref2, W_mh, W_q2,
                                      wfrag, wrefT, wref2T, wmh_bf, wq2_bf);
    embed_k<<<RT, 256, 0, stream>>>(nf, W_emb, hA);

    hop_fused<<<B, 512, 0, stream>>>(hA, adj, wfrag, hB);            // hop 0
    hop_fused<<<B, 512, 0, stream>>>(hB, adj, wfrag + 262144, hA);   // hop 1

    const bf16* enc = hA;

    mean_k<<<B, 256, 0, stream>>>(enc, enc_mean);
    prep_k<<<M, 256, 0, stream>>>(W_q, Vec, dec, v_1, qconst, vsumb);
    q_k<<<B * M, 256, 0, stream>>>(enc_mean, W_q, qconst, qbuf);
    head2_mfma<<<dim3(RT / 128, M), 256, 0, stream>>>(enc, wrefT, qbuf, M * H, vsumb, scoresb, M * N);
    softmax_ctx_k<<<B * M, 256, 0, stream>>>(scoresb, mask, enc, ctxb);
    query2_k<<<B, 256, 0, stream>>>(ctxb, wmh_bf, wq2_bf, q2b);
    head2_mfma<<<dim3(RT / 128, 1), 256, 0, stream>>>(enc, wref2T, q2b, H, Vec2, u2b, N);
    final_out_k<<<B, 128, 0, stream>>>(u2b, mask, out);
}

// Round 5
// 293.542 us; speedup vs baseline: 7.8811x; 1.0821x over previous
//
#include <hip/hip_runtime.h>
#include <hip/hip_bf16.h>

#define B 512
#define N 102
#define Pdim 12
#define H 256
#define M 4
#define E 3
#define NEG (-1e9f)
#define RT 52224   // B*N
#define NN (N * N)

typedef __hip_bfloat16 bf16;
typedef __attribute__((ext_vector_type(8))) short short8;
typedef __attribute__((ext_vector_type(4))) float f32x4;
typedef __attribute__((ext_vector_type(16))) float f32x16;

__device__ __forceinline__ float b2f(bf16 v) { return __bfloat162float(v); }
__device__ __forceinline__ bf16 f2b(float v) { return __float2bfloat16(v); }
__device__ __forceinline__ short f2bs(float v) {
    bf16 t = __float2bfloat16(v);
    return *reinterpret_cast<short*>(&t);
}
__device__ __forceinline__ float fast_tanh(float x) {
    float e = __expf(2.f * x);
    return 1.f - 2.f * __builtin_amdgcn_rcpf(e + 1.f);
}

// ---------------- weight prep (all weight-only precompute folded here) ----------------
// wfrag [hop][ct:16][ks:32][lane:64][j:8]; wrefT[(m*256+c)][k]; wref2T[c][k];
// wmh_bf [1024][256]; wq2_bf [256][256]; wq_bf [m][256f][256h];
// blocks >= 5632: prep (qconst, vsum)
__global__ __launch_bounds__(256) void wt_prep(const float* __restrict__ Wrel,
                                               const float* __restrict__ Wself,
                                               const float* __restrict__ Wref,
                                               const float* __restrict__ Wref2,
                                               const float* __restrict__ Wmh,
                                               const float* __restrict__ Wq2,
                                               const float* __restrict__ W_q,
                                               const float* __restrict__ Vec,
                                               const float* __restrict__ dec,
                                               const float* __restrict__ v1,
                                               short* __restrict__ wfrag,
                                               short* __restrict__ wrefT,
                                               short* __restrict__ wref2T,
                                               short* __restrict__ wmh_bf,
                                               short* __restrict__ wq2_bf,
                                               short* __restrict__ wq_bf,
                                               float* __restrict__ qconst,
                                               float* __restrict__ vsum) {
    if (blockIdx.x >= 5632) {
        // prep: qconst[m,h], vsum[m,h]
        int m = blockIdx.x - 5632, hh = threadIdx.x;
        __shared__ float dls[H], vls[H];
        dls[hh] = dec[hh];
        vls[hh] = v1[hh];
        __syncthreads();
        const float* Wm = W_q + (size_t)m * (3 * H) * H;
        float s = 0.f;
        for (int f = 0; f < H; ++f)
            s += dls[f] * Wm[(H + f) * H + hh] + vls[f] * Wm[(2 * H + f) * H + hh];
        qconst[m * H + hh] = s;
        float vs = 0.f;
        const float* Vr = Vec + ((size_t)m * H + hh) * H;
        for (int k = 0; k < H; ++k) vs += Vr[k];
        vsum[m * H + hh] = vs;
        return;
    }
    int idx = blockIdx.x * 256 + threadIdx.x;
    if (idx < 524288) {
        int j = idx & 7;
        int lq = (idx >> 3) & 63;
        int ks = (idx >> 9) & 31;
        int ct = (idx >> 14) & 15;
        int hop = idx >> 18;
        int c = ct * 16 + (lq & 15);
        int k = ks * 32 + ((lq >> 4) & 3) * 8 + j;
        float v;
        if (k < 768) {
            int e = k >> 8, kk = k & 255;
            v = Wrel[(((size_t)hop * E + e) * H + kk) * H + c];
        } else {
            v = Wself[((size_t)hop * H + (k - 768)) * H + c];
        }
        wfrag[idx] = f2bs(v);
    } else if (idx < 786432) {
        int r = idx - 524288;
        int row = r >> 8, k = r & 255;
        int m = row >> 8, c = row & 255;
        wrefT[r] = f2bs(Wref[((size_t)m * H + k) * H + c]);
    } else if (idx < 851968) {
        int r = idx - 786432;
        int c = r >> 8, k = r & 255;
        wref2T[r] = f2bs(Wref2[k * H + c]);
    } else if (idx < 1114112) {
        int r = idx - 851968;
        wmh_bf[r] = f2bs(Wmh[r]);
    } else if (idx < 1179648) {
        int r = idx - 1114112;
        wq2_bf[r] = f2bs(Wq2[r]);
    } else if (idx < 1441792) {
        int r = idx - 1179648;          // m*65536 + f*256 + hh
        int m = r >> 16, fh = r & 65535;
        wq_bf[r] = f2bs(W_q[(size_t)m * 768 * 256 + fh]);
    }
}

// ---------------- embedding h = nf @ W_emb, 64 rows per block ----------------
__global__ __launch_bounds__(256) void embed_k(const float* __restrict__ nf,
                                               const float* __restrict__ W_emb,
                                               bf16* __restrict__ h) {
    int r0 = blockIdx.x * 64;
    int tid = threadIdx.x;
    __shared__ float fs[64][Pdim];
    for (int i = tid; i < 64 * Pdim; i += 256)
        fs[i / Pdim][i % Pdim] = nf[(size_t)r0 * Pdim + i];
    float w[Pdim];
#pragma unroll
    for (int p = 0; p < Pdim; ++p) w[p] = W_emb[p * H + tid];
    __syncthreads();
    for (int r = 0; r < 64; ++r) {
        float s = 0.f;
#pragma unroll
        for (int p = 0; p < Pdim; ++p) s += fs[r][p] * w[p];
        h[(size_t)(r0 + r) * H + tid] = f2b(s);
    }
}

// ------------- fused hop: h_next = relu( sum_e A_e (h Wrel[e]) + h Wself ) -------------
// 1024 threads = 16 waves; wave w owns c-tile [w*16, w*16+16).
// T14: adjacency for e+1 loaded to regs during e's compute.
#define HP 264     // h LDS pitch (shorts)
#define YP 136     // Yt/As pitch (shorts)
#define AREG 11    // ceil(10404/1024)
__global__ __launch_bounds__(1024, 4) void hop_fused(const bf16* __restrict__ hin,
                                                     const float* __restrict__ adj,
                                                     const short* __restrict__ wfragp,
                                                     bf16* __restrict__ hout,
                                                     float* __restrict__ mean_out) {
    int b = blockIdx.x;
    int tid = threadIdx.x;
    int w = tid >> 6;          // 0..15 = ct
    int l = tid & 63;
    int cg = l & 15;
    int rg = (l >> 4) & 3;

    __shared__ short hS[112 * HP];
    __shared__ short YtS[256 * YP];
    __shared__ short AsS[112 * YP];

    const short8 z8 = {0, 0, 0, 0, 0, 0, 0, 0};
    // zero: AsS fully; hS rows [102,112); YtS cols [112,128)
    for (int i = tid; i < (112 * YP) / 8; i += 1024) ((short8*)AsS)[i] = z8;
    for (int i = tid; i < 10 * 32; i += 1024) {
        int n = 102 + (i >> 5), g = i & 31;
        *(short8*)(&hS[n * HP + g * 8]) = z8;
    }
    for (int i = tid; i < 512; i += 1024) {
        int c = i >> 1, part = i & 1;
        *(short8*)(&YtS[c * YP + 112 + part * 8]) = z8;
    }
    // stage h[b]
    const short* hp = (const short*)hin;
    for (int i = tid; i < 102 * 32; i += 1024) {
        int n = i >> 5, g = i & 31;
        *(short8*)(&hS[n * HP + g * 8]) = *(const short8*)(hp + ((size_t)b * N + n) * H + g * 8);
    }

    // adjacency prefetch bookkeeping
    int offA[AREG];
    bool valA[AREG];
#pragma unroll
    for (int i = 0; i < AREG; ++i) {
        int id = tid + (i << 10);
        valA[i] = (id < NN);
        int n = id / N, m = id - n * N;
        offA[i] = valA[i] ? (n * YP + m) : 0;
    }
    const float* Ab0 = adj + ((size_t)b * E) * NN;
    float areg[AREG];
#pragma unroll
    for (int i = 0; i < AREG; ++i) {
        int id = tid + (i << 10);
        areg[i] = valA[i] ? Ab0[id] : 0.f;
    }
    __syncthreads();

    const short8* wf8 = (const short8*)wfragp;

    f32x4 hacc[7];
#pragma unroll
    for (int j = 0; j < 7; ++j) hacc[j] = (f32x4){0.f, 0.f, 0.f, 0.f};

    for (int e = 0; e < E; ++e) {
        // --- Y-phase: g[mt] = W_rel^T[e] x h^T for this wave's c-tile ---
        f32x4 g[7];
#pragma unroll
        for (int j = 0; j < 7; ++j) g[j] = (f32x4){0.f, 0.f, 0.f, 0.f};
#pragma unroll
        for (int ks = 0; ks < 8; ++ks) {
            short8 wfa = wf8[(w * 32 + e * 8 + ks) * 64 + l];
#pragma unroll
            for (int mt = 0; mt < 7; ++mt) {
                short8 hf = *(const short8*)(&hS[(mt * 16 + cg) * HP + ks * 32 + rg * 8]);
                g[mt] = __builtin_amdgcn_mfma_f32_16x16x32_bf16(wfa, hf, g[mt], 0, 0, 0);
            }
        }
        // --- write As (loaded a phase ago) + prefetch next e ---
#pragma unroll
        for (int i = 0; i < AREG; ++i)
            if (valA[i]) AsS[offA[i]] = f2bs(areg[i]);
        if (e < E - 1) {
            const float* Abn = adj + ((size_t)b * E + e + 1) * NN;
#pragma unroll
            for (int i = 0; i < AREG; ++i) {
                int id = tid + (i << 10);
                if (valA[i]) areg[i] = Abn[id];
            }
        }
        // --- write Ye^T to LDS ---
#pragma unroll
        for (int mt = 0; mt < 7; ++mt)
#pragma unroll
            for (int r = 0; r < 4; ++r) {
                int c = w * 16 + rg * 4 + r;
                YtS[c * YP + mt * 16 + cg] = f2bs(g[mt][r]);
            }
        __syncthreads();
        // --- gather: hacc[n][c] += sum_m As[n][m] * Yt[c][m] ---
#pragma unroll
        for (int ks = 0; ks < 4; ++ks) {
            short8 yf = *(const short8*)(&YtS[(w * 16 + cg) * YP + ks * 32 + rg * 8]);
#pragma unroll
            for (int nt = 0; nt < 7; ++nt) {
                short8 af = *(const short8*)(&AsS[(nt * 16 + cg) * YP + ks * 32 + rg * 8]);
                hacc[nt] = __builtin_amdgcn_mfma_f32_16x16x32_bf16(af, yf, hacc[nt], 0, 0, 0);
            }
        }
        __syncthreads();
    }
    // --- self: hacc[n][c] += sum_k h[n][k] Wself[k][c] ---
#pragma unroll
    for (int ks = 0; ks < 8; ++ks) {
        short8 wfa = wf8[(w * 32 + 24 + ks) * 64 + l];
#pragma unroll
        for (int nt = 0; nt < 7; ++nt) {
            short8 hf = *(const short8*)(&hS[(nt * 16 + cg) * HP + ks * 32 + rg * 8]);
            hacc[nt] = __builtin_amdgcn_mfma_f32_16x16x32_bf16(hf, wfa, hacc[nt], 0, 0, 0);
        }
    }
    __syncthreads();   // all hS reads done; reuse as output staging
    // relu + pack
#pragma unroll
    for (int nt = 0; nt < 7; ++nt)
#pragma unroll
        for (int r = 0; r < 4; ++r) {
            int n = nt * 16 + rg * 4 + r;
            int c = w * 16 + cg;
            float v = hacc[nt][r];
            hS[n * HP + c] = f2bs(v > 0.f ? v : 0.f);
        }
    __syncthreads();
    short* ho = (short*)hout;
    for (int i = tid; i < 102 * 32; i += 1024) {
        int n = i >> 5, g = i & 31;
        *(short8*)(ho + ((size_t)b * N + n) * H + g * 8) = *(const short8*)(&hS[n * HP + g * 8]);
    }
    if (mean_out) {
        float* partf = (float*)AsS;
        int c = tid & 255, qq = tid >> 8;
        float s = 0.f;
        for (int n = qq; n < N; n += 4) s += b2f(*(const bf16*)&hS[n * HP + c]);
        partf[qq * 256 + c] = s;
        __syncthreads();
        if (tid < 256)
            mean_out[(size_t)b * H + tid] =
                (partf[tid] + partf[256 + tid] + partf[512 + tid] + partf[768 + tid]) * (1.f / (float)N);
    }
}

// ------- head2: swapped-operand 32x32x16; per-lane in-register c-reduction -------
__global__ __launch_bounds__(256, 2) void head2_mfma(const bf16* __restrict__ X,
                                                     const short* __restrict__ WT,
                                                     const float* __restrict__ qb, int qbs,
                                                     const float* __restrict__ vsb,
                                                     float* __restrict__ outp, int obs) {
    int rt = blockIdx.x, m = blockIdx.y;
    int r0 = rt * 128;
    int tid = threadIdx.x;
    int w = tid >> 6, l = tid & 63;
    int lr = l & 31;
    int lh = l >> 5;
    __shared__ short Xs[128 * 256];
    __shared__ float qls[3 * 256];
    __shared__ float part[4][128];

    const short* Xp = (const short*)X;
#pragma unroll
    for (int i = 0; i < 16; ++i) {
        int id = tid + i * 256;
        int r = id >> 5, g = id & 31;
        short8 v = *(const short8*)(Xp + (size_t)(r0 + r) * H + g * 8);
        *(short8*)((char*)Xs + r * 512 + ((g ^ (r & 7)) * 16)) = v;
    }
    int b_base = r0 / N;
#pragma unroll
    for (int i = 0; i < 3; ++i) {
        int bb = b_base + i;
        if (bb > B - 1) bb = B - 1;
        qls[i * 256 + tid] = qb[(size_t)bb * qbs + m * H + tid];
    }
    const short8* w8 = (const short8*)WT;
    int cbase = m * 256 + w * 64;
    short8 afr0[16], afr1[16];
#pragma unroll
    for (int ks = 0; ks < 16; ++ks) {
        afr0[ks] = w8[(size_t)(cbase + lr) * 32 + ks * 2 + lh];
        afr1[ks] = w8[(size_t)(cbase + 32 + lr) * 32 + ks * 2 + lh];
    }
    float vsl[32];
#pragma unroll
    for (int j = 0; j < 16; ++j) {
        int cl = (j & 3) + 8 * (j >> 2) + 4 * lh;
        vsl[j]      = vsb[m * H + w * 64 + cl];
        vsl[16 + j] = vsb[m * H + w * 64 + 32 + cl];
    }
    __syncthreads();

    int swz = lr & 7;
    for (int t = 0; t < 4; ++t) {
        f32x16 acc0, acc1;
#pragma unroll
        for (int j = 0; j < 16; ++j) { acc0[j] = 0.f; acc1[j] = 0.f; }
        const char* xbase = (const char*)Xs + (t * 32 + lr) * 512;
#pragma unroll
        for (int ks = 0; ks < 16; ++ks) {
            short8 bx = *(const short8*)(xbase + (((2 * ks + lh) ^ swz) * 16));
            acc0 = __builtin_amdgcn_mfma_f32_32x32x16_bf16(afr0[ks], bx, acc0, 0, 0, 0);
            acc1 = __builtin_amdgcn_mfma_f32_32x32x16_bf16(afr1[ks], bx, acc1, 0, 0, 0);
        }
        int r = r0 + t * 32 + lr;
        int b = r / N;
        int boff = b - b_base;
        float s = 0.f;
#pragma unroll
        for (int j = 0; j < 16; ++j) {
            int cl = (j & 3) + 8 * (j >> 2) + 4 * lh;
            float x0 = qls[boff * 256 + w * 64 + cl] + acc0[j];
            s += fast_tanh(x0) * vsl[j];
            float x1 = qls[boff * 256 + w * 64 + 32 + cl] + acc1[j];
            s += fast_tanh(x1) * vsl[16 + j];
        }
        s += __shfl_xor(s, 32, 64);
        if (l < 32) part[w][t * 32 + lr] = s;
    }
    __syncthreads();
    if (tid < 128) {
        int r = r0 + tid;
        int b = r / N, n = r - b * N;
        outp[(size_t)b * obs + m * N + n] = part[0][tid] + part[1][tid] + part[2][tid] + part[3][tid];
    }
}

// ---------------- q[b,m,h] (bf16 W_q) ----------------
__global__ __launch_bounds__(256) void q_k(const float* __restrict__ enc_mean,
                                           const short* __restrict__ wq_bf,
                                           const float* __restrict__ qconst,
                                           float* __restrict__ qbuf) {
    int bid = blockIdx.x;
    int b = bid >> 2, m = bid & 3;
    int hh = threadIdx.x;
    __shared__ float em[H];
    em[hh] = enc_mean[(size_t)b * H + hh];
    __syncthreads();
    const bf16* Wm = (const bf16*)(wq_bf + (size_t)m * 65536);
    float s = qconst[m * H + hh];
    for (int f = 0; f < H; ++f) s += em[f] * b2f(Wm[f * H + hh]);
    qbuf[((size_t)b * M + m) * H + hh] = s;
}

// ---------------- masked softmax + ctx ----------------
__global__ __launch_bounds__(256) void softmax_ctx_k(const float* __restrict__ scores,
                                                     const int* __restrict__ mask,
                                                     const bf16* __restrict__ enc,
                                                     float* __restrict__ ctx) {
    int bid = blockIdx.x;
    int b = bid >> 2, m = bid & 3;
    int tid = threadIdx.x;
    __shared__ float a[128];
    __shared__ float red[2];
    float sv = NEG;
    if (tid < N)
        sv = (mask[(size_t)b * N + tid] > 0) ? NEG : scores[((size_t)b * M + m) * N + tid];
    if (tid < 128) a[tid] = sv;
    __syncthreads();
    if (tid < 64) {
        float v = fmaxf(a[tid], a[tid + 64]);
        v = fmaxf(v, __shfl_xor(v, 32, 64));
        v = fmaxf(v, __shfl_xor(v, 16, 64));
        v = fmaxf(v, __shfl_xor(v, 8, 64));
        v = fmaxf(v, __shfl_xor(v, 4, 64));
        v = fmaxf(v, __shfl_xor(v, 2, 64));
        v = fmaxf(v, __shfl_xor(v, 1, 64));
        if (tid == 0) red[0] = v;
    }
    __syncthreads();
    float mx = red[0];
    float ev = (tid < N) ? __expf(sv - mx) : 0.f;
    if (tid < 128) a[tid] = ev;
    __syncthreads();
    if (tid < 64) {
        float v = a[tid] + a[tid + 64];
        v += __shfl_xor(v, 32, 64);
        v += __shfl_xor(v, 16, 64);
        v += __shfl_xor(v, 8, 64);
        v += __shfl_xor(v, 4, 64);
        v += __shfl_xor(v, 2, 64);
        v += __shfl_xor(v, 1, 64);
        if (tid == 0) red[1] = __builtin_amdgcn_rcpf(v);
    }
    __syncthreads();
    float inv = red[1];
    float c = 0.f;
    for (int n = 0; n < N; ++n)
        c += a[n] * b2f(enc[((size_t)b * N + n) * H + tid]);
    ctx[((size_t)b * M + m) * H + tid] = c * inv;
}

// ---------------- query2 = (ctx @ W_mh) @ W_q2 ----------------
__global__ __launch_bounds__(256) void query2_k(const float* __restrict__ ctx,
                                                const short* __restrict__ wmh,
                                                const short* __restrict__ wq2,
                                                float* __restrict__ q2) {
    int b = blockIdx.x;
    int tid = threadIdx.x;
    __shared__ float cx[M * H];
    __shared__ float qy[H];
    for (int idx = tid; idx < M * H; idx += 256) cx[idx] = ctx[(size_t)b * M * H + idx];
    __syncthreads();
    const bf16* wm = (const bf16*)wmh;
    float acc = 0.f;
    for (int j = 0; j < M * H; ++j) acc += cx[j] * b2f(wm[(size_t)j * H + tid]);
    qy[tid] = acc;
    __syncthreads();
    const bf16* w2 = (const bf16*)wq2;
    float acc2 = 0.f;
    for (int k = 0; k < H; ++k) acc2 += qy[k] * b2f(w2[(size_t)k * H + tid]);
    q2[(size_t)b * H + tid] = acc2;
}

// ---------------- clip + mask + log_softmax (wave-parallel) ----------------
__global__ __launch_bounds__(128) void final_out_k(const float* __restrict__ u2,
                                                   const int* __restrict__ mask,
                                                   float* __restrict__ out) {
    int b = blockIdx.x;
    int tid = threadIdx.x;
    __shared__ float a[128];
    __shared__ float red[2];
    float u = NEG;
    if (tid < N) {
        u = 10.f * fast_tanh(u2[(size_t)b * N + tid]);
        if (mask[(size_t)b * N + tid] > 0) u = NEG;
    }
    a[tid] = u;
    __syncthreads();
    if (tid < 64) {
        float v = fmaxf(a[tid], a[tid + 64]);
        v = fmaxf(v, __shfl_xor(v, 32, 64));
        v = fmaxf(v, __shfl_xor(v, 16, 64));
        v = fmaxf(v, __shfl_xor(v, 8, 64));
        v = fmaxf(v, __shfl_xor(v, 4, 64));
        v = fmaxf(v, __shfl_xor(v, 2, 64));
        v = fmaxf(v, __shfl_xor(v, 1, 64));
        if (tid == 0) red[0] = v;
    }
    __syncthreads();
    float mx = red[0];
    float ev = (tid < N) ? __expf(u - mx) : 0.f;
    a[tid] = ev;
    __syncthreads();
    if (tid < 64) {
        float v = a[tid] + a[tid + 64];
        v += __shfl_xor(v, 32, 64);
        v += __shfl_xor(v, 16, 64);
        v += __shfl_xor(v, 8, 64);
        v += __shfl_xor(v, 4, 64);
        v += __shfl_xor(v, 2, 64);
        v += __shfl_xor(v, 1, 64);
        if (tid == 0) red[1] = logf(v);
    }
    __syncthreads();
    if (tid < N) out[(size_t)b * N + tid] = (u - mx) - red[1];
}

extern "C" void kernel_launch(void* const* d_in, const int* in_sizes, int n_in,
                              void* d_out, int out_size, void* d_ws, size_t ws_size,
                              hipStream_t stream) {
    const float* nf     = (const float*)d_in[0];
    const float* adj    = (const float*)d_in[1];
    const int*   mask   = (const int*)d_in[2];
    const float* W_emb  = (const float*)d_in[3];
    const float* W_rel  = (const float*)d_in[4];
    const float* W_self = (const float*)d_in[5];
    const float* Vec    = (const float*)d_in[6];
    const float* W_q    = (const float*)d_in[7];
    const float* W_ref  = (const float*)d_in[8];
    const float* W_mh   = (const float*)d_in[9];
    const float* Vec2   = (const float*)d_in[10];
    const float* W_q2   = (const float*)d_in[11];
    const float* W_ref2 = (const float*)d_in[12];
    const float* dec    = (const float*)d_in[13];
    const float* v_1    = (const float*)d_in[14];
    float* out = (float*)d_out;

    char* p = (char*)d_ws;
    size_t off = 0;
    auto alloc = [&](size_t bytes) -> char* {
        char* q = p + off;
        off += (bytes + 255) & ~(size_t)255;
        return q;
    };
    bf16* hA    = (bf16*)alloc((size_t)RT * H * sizeof(bf16));
    bf16* hB    = (bf16*)alloc((size_t)RT * H * sizeof(bf16));
    short* wfrag  = (short*)alloc(524288 * sizeof(short));
    short* wrefT  = (short*)alloc(262144 * sizeof(short));
    short* wref2T = (short*)alloc(65536 * sizeof(short));
    short* wmh_bf = (short*)alloc(262144 * sizeof(short));
    short* wq2_bf = (short*)alloc(65536 * sizeof(short));
    short* wq_bf  = (short*)alloc(262144 * sizeof(short));
    float* enc_mean = (float*)alloc((size_t)B * H * sizeof(float));
    float* qconst   = (float*)alloc((size_t)M * H * sizeof(float));
    float* vsumb    = (float*)alloc((size_t)M * H * sizeof(float));
    float* qbuf     = (float*)alloc((size_t)B * M * H * sizeof(float));
    float* scoresb  = (float*)alloc((size_t)B * M * N * sizeof(float));
    float* ctxb     = (float*)alloc((size_t)B * M * H * sizeof(float));
    float* q2b      = (float*)alloc((size_t)B * H * sizeof(float));
    float* u2b      = (float*)alloc((size_t)B * N * sizeof(float));

    wt_prep<<<5636, 256, 0, stream>>>(W_rel, W_self, W_ref, W_ref2, W_mh, W_q2,
                                      W_q, Vec, dec, v_1,
                                      wfrag, wrefT, wref2T, wmh_bf, wq2_bf, wq_bf,
                                      qconst, vsumb);
    embed_k<<<RT / 64, 256, 0, stream>>>(nf, W_emb, hA);

    hop_fused<<<B, 1024, 0, stream>>>(hA, adj, wfrag, hB, nullptr);              // hop 0
    hop_fused<<<B, 1024, 0, stream>>>(hB, adj, wfrag + 262144, hA, enc_mean);    // hop 1

    const bf16* enc = hA;

    q_k<<<B * M, 256, 0, stream>>>(enc_mean, wq_bf, qconst, qbuf);
    head2_mfma<<<dim3(RT / 128, M), 256, 0, stream>>>(enc, wrefT, qbuf, M * H, vsumb, scoresb, M * N);
    softmax_ctx_k<<<B * M, 256, 0, stream>>>(scoresb, mask, enc, ctxb);
    query2_k<<<B, 256, 0, stream>>>(ctxb, wmh_bf, wq2_bf, q2b);
    head2_mfma<<<dim3(RT / 128, 1), 256, 0, stream>>>(enc, wref2T, q2b, H, Vec2, u2b, N);
    final_out_k<<<B, 128, 0, stream>>>(u2b, mask, out);
}